// Round 20
// baseline (122.818 us; speedup 1.0000x reference)
//
#include <hip/hip_runtime.h>
#include <math.h>

#define C_DIM 256
#define HH 32
#define WW 32
#define ZZ 8
#define HD 32

typedef __attribute__((ext_vector_type(8))) short bf16x8;
typedef __attribute__((ext_vector_type(4))) float f32x4;
typedef __attribute__((ext_vector_type(4))) unsigned int u32x4;

__device__ inline unsigned short f2bf(float f) {
    unsigned int u = __builtin_bit_cast(unsigned int, f);
    u += 0x7FFF + ((u >> 16) & 1);
    return (unsigned short)(u >> 16);
}
__device__ inline float bf2f(unsigned short h) {
    unsigned int u = ((unsigned int)h) << 16;
    return __builtin_bit_cast(float, u);
}
__device__ inline unsigned int cvtpk_bf16(float a, float b) {
    unsigned int r;
    asm("v_cvt_pk_bf16_f32 %0, %1, %2" : "=v"(r) : "v"(a), "v"(b));
    return r;  // lo = bf16(a), hi = bf16(b)
}

// softmax scale with log2(e) folded in: exp2(q*k*QSCALE) == exp(q*k/sqrt(32))
#define QSCALE (0.17677669529663689f * 1.4426950408889634f)

// ---------------------------------------------------------------------------
// Split-bf16 MFMA GEMM with split-K, double-buffered LDS + reg prefetch.
// C[i,j] = sum_k A[i,k]*B[j,k] (+bias[j] if gridDim.z==1 && bias)
// hi/lo split via v_cvt_pk_bf16_f32 (exact residual by Sterbenz).
// Epilogue modes:
//   qb_out != null : write f2bf(val*QSCALE) to qb_out[row*N+col]; skip C.
//   kb_out != null : write C as usual; ALSO if col<128 write tiled bf16 K:
//                    kb_out[((h*KTp+kt)*128+mi)*32+c].
// ---------------------------------------------------------------------------
__global__ __launch_bounds__(256) void gemm_split_kernel(
    const float* __restrict__ A, const float* __restrict__ B,
    const float* __restrict__ bias, float* __restrict__ C,
    int M, int N, int K,
    unsigned short* __restrict__ qb_out,
    unsigned short* __restrict__ kb_out, int KTp) {
    __shared__ unsigned short Ah[2][2560], Al[2][2560], Bh[2][2560], Bl[2][2560];
    int t = threadIdx.x;
    int wave = t >> 6, lane = t & 63;
    int lg = lane >> 4, lc = lane & 15;
    int wm = wave >> 1, wn = wave & 1;
    int m0 = blockIdx.y * 64, n0 = blockIdx.x * 64;
    int Kc = K / gridDim.z;
    int kbeg = blockIdx.z * Kc;
    float* Cz = C + (long)blockIdx.z * M * N;
    int srow = t >> 2, sc8 = (t & 3) * 8;
    const float* aBase = A + (long)(m0 + srow) * K + kbeg + sc8;
    const float* bBase = B + (long)(n0 + srow) * K + kbeg + sc8;
    int nIter = Kc / 32;

    f32x4 acc[2][2];
#pragma unroll
    for (int i = 0; i < 2; ++i)
#pragma unroll
        for (int j = 0; j < 2; ++j) acc[i][j] = (f32x4){0.f, 0.f, 0.f, 0.f};

    // split 8 f32 into hi/lo bf16 planes via cvt_pk; residual exact (Sterbenz)
    auto split8 = [](f32x4 v0, f32x4 v1, u32x4& hw, u32x4& lw) {
        float av[8] = {v0[0], v0[1], v0[2], v0[3], v1[0], v1[1], v1[2], v1[3]};
#pragma unroll
        for (int p = 0; p < 4; ++p) {
            float x0 = av[2 * p], x1 = av[2 * p + 1];
            unsigned int w = cvtpk_bf16(x0, x1);
            float h0 = __builtin_bit_cast(float, w << 16);
            float h1 = __builtin_bit_cast(float, w & 0xFFFF0000u);
            hw[p] = w;
            lw[p] = cvtpk_bf16(x0 - h0, x1 - h1);
        }
    };
    auto cvt_store = [&](int buf, f32x4 a0, f32x4 a1, f32x4 b0, f32x4 b1) {
        u32x4 hw, lw;
        split8(a0, a1, hw, lw);
        *reinterpret_cast<u32x4*>(&Ah[buf][srow * 40 + sc8]) = hw;
        *reinterpret_cast<u32x4*>(&Al[buf][srow * 40 + sc8]) = lw;
        split8(b0, b1, hw, lw);
        *reinterpret_cast<u32x4*>(&Bh[buf][srow * 40 + sc8]) = hw;
        *reinterpret_cast<u32x4*>(&Bl[buf][srow * 40 + sc8]) = lw;
    };

    {
        f32x4 a0 = *reinterpret_cast<const f32x4*>(aBase);
        f32x4 a1 = *reinterpret_cast<const f32x4*>(aBase + 4);
        f32x4 b0 = *reinterpret_cast<const f32x4*>(bBase);
        f32x4 b1 = *reinterpret_cast<const f32x4*>(bBase + 4);
        cvt_store(0, a0, a1, b0, b1);
    }
    __syncthreads();

    for (int k = 0; k < nIter; ++k) {
        int cur = k & 1;
        bool more = (k + 1 < nIter);
        f32x4 na0, na1, nb0, nb1;
        if (more) {
            const float* ap = aBase + (k + 1) * 32;
            const float* bp = bBase + (k + 1) * 32;
            na0 = *reinterpret_cast<const f32x4*>(ap);
            na1 = *reinterpret_cast<const f32x4*>(ap + 4);
            nb0 = *reinterpret_cast<const f32x4*>(bp);
            nb1 = *reinterpret_cast<const f32x4*>(bp + 4);
        }
        bf16x8 afh[2], afl[2], bfh[2], bfl[2];
#pragma unroll
        for (int i = 0; i < 2; ++i) {
            int ar = wm * 32 + i * 16 + lc;
            afh[i] = *reinterpret_cast<const bf16x8*>(&Ah[cur][ar * 40 + lg * 8]);
            afl[i] = *reinterpret_cast<const bf16x8*>(&Al[cur][ar * 40 + lg * 8]);
            int br = wn * 32 + i * 16 + lc;
            bfh[i] = *reinterpret_cast<const bf16x8*>(&Bh[cur][br * 40 + lg * 8]);
            bfl[i] = *reinterpret_cast<const bf16x8*>(&Bl[cur][br * 40 + lg * 8]);
        }
#pragma unroll
        for (int i = 0; i < 2; ++i)
#pragma unroll
            for (int j = 0; j < 2; ++j) {
                acc[i][j] = __builtin_amdgcn_mfma_f32_16x16x32_bf16(afh[i], bfh[j], acc[i][j], 0, 0, 0);
                acc[i][j] = __builtin_amdgcn_mfma_f32_16x16x32_bf16(afh[i], bfl[j], acc[i][j], 0, 0, 0);
                acc[i][j] = __builtin_amdgcn_mfma_f32_16x16x32_bf16(afl[i], bfh[j], acc[i][j], 0, 0, 0);
            }
        if (more) {
            cvt_store(cur ^ 1, na0, na1, nb0, nb1);
            __syncthreads();
        }
    }
#pragma unroll
    for (int i = 0; i < 2; ++i)
#pragma unroll
        for (int j = 0; j < 2; ++j)
#pragma unroll
            for (int r = 0; r < 4; ++r) {
                int row = m0 + wm * 32 + i * 16 + lg * 4 + r;
                int col = n0 + wn * 32 + j * 16 + lc;
                float bv = bias ? bias[col] : 0.f;
                float val = acc[i][j][r] + bv;
                if (qb_out) {
                    qb_out[(long)row * N + col] = f2bf(val * QSCALE);
                } else {
                    Cz[(long)row * N + col] = val;
                    if (kb_out && col < 128) {
                        int h = col >> 5, c = col & 31, kt = row >> 7, mi = row & 127;
                        kb_out[((long)(h * KTp + kt) * 128 + mi) * 32 + c] = f2bf(val);
                    }
                }
            }
}

// ---------------------------------------------------------------------------
// Fused: sum KS split-K planes + bias, then LayerNorm + exact GELU.
// ---------------------------------------------------------------------------
__global__ void reduce_ln_gelu_kernel(const float* __restrict__ part,
                                      const float* __restrict__ bias,
                                      const float* __restrict__ g,
                                      const float* __restrict__ bb,
                                      float* __restrict__ xr, int MN, int KS) {
    int m = blockIdx.x;
    int c = threadIdx.x;
    float v = bias[c];
    for (int z = 0; z < KS; ++z) v += part[(long)z * MN + m * C_DIM + c];
    __shared__ float wred[4];
    float s = v;
    for (int off = 32; off; off >>= 1) s += __shfl_down(s, off);
    if ((c & 63) == 0) wred[c >> 6] = s;
    __syncthreads();
    float mean = (wred[0] + wred[1] + wred[2] + wred[3]) * (1.f / 256.f);
    __syncthreads();
    float d = v - mean;
    float s2 = d * d;
    for (int off = 32; off; off >>= 1) s2 += __shfl_down(s2, off);
    if ((c & 63) == 0) wred[c >> 6] = s2;
    __syncthreads();
    float var = (wred[0] + wred[1] + wred[2] + wred[3]) * (1.f / 256.f);
    float y = d * rsqrtf(var + 1e-5f) * g[c] + bb[c];
    float ge = 0.5f * y * (1.f + erff(y * 0.70710678118654752f));
    xr[m * C_DIM + c] = ge;
}

// ---------------------------------------------------------------------------
// im2col for SR conv.
// ---------------------------------------------------------------------------
template <int S>
__global__ void im2col_kernel(const float* __restrict__ x, float* __restrict__ im, int Ws) {
    constexpr int T = S * S;
    __shared__ float patch[T * 257];
    int m = blockIdx.x;
    int z = m % ZZ;
    int wo = (m / ZZ) % Ws;
    int ho = m / (ZZ * Ws);
    int t = threadIdx.x;
#pragma unroll
    for (int tap = 0; tap < T; ++tap) {
        int kh = tap / S, kw = tap % S;
        int row = (ho * S + kh) * (WW * ZZ) + (wo * S + kw) * ZZ + z;
        patch[tap * 257 + t] = x[row * C_DIM + t];
    }
    __syncthreads();
#pragma unroll
    for (int rep = 0; rep < T; ++rep) {
        int k = rep * 256 + t;
        int ci = k / T, tap = k % T;
        im[(long)m * (256 * T) + k] = patch[tap * 257 + ci];
    }
}

// ---------------------------------------------------------------------------
// Depthwise 3x3x1 conv on V + residual; writes tiled V^T bf16:
// vt[((hh*KT+kt)*32 + d)*128 + s], slot s per the in-register P order of the
// swapped-QK attention: mi = a<<5|u<<4|g<<2|v -> s = a<<5|g<<3|u<<2|v.
// ---------------------------------------------------------------------------
__global__ void dw_conv_kernel(const float* __restrict__ kv, const float* __restrict__ lw,
                               const float* __restrict__ lb, unsigned short* __restrict__ vt,
                               int Ws, int Hs, int KT) {
    int m = blockIdx.x;
    int ch = threadIdx.x;
    int z = m % ZZ;
    int wo = (m / ZZ) % Ws;
    int ho = m / (ZZ * Ws);
    float acc = lb[ch];
#pragma unroll
    for (int kh = 0; kh < 3; ++kh) {
        int h = ho + kh - 1;
        if (h < 0 || h >= Hs) continue;
#pragma unroll
        for (int kw = 0; kw < 3; ++kw) {
            int w2 = wo + kw - 1;
            if (w2 < 0 || w2 >= Ws) continue;
            int mm = (h * Ws + w2) * ZZ + z;
            acc += kv[mm * C_DIM + 128 + ch] * lw[ch * 9 + kh * 3 + kw];
        }
    }
    int hh = ch >> 5, d = ch & 31, kt = m >> 7, mi = m & 127;
    int a = mi >> 5, u = (mi >> 4) & 1, g = (mi >> 2) & 3, v = mi & 3;
    int s = (a << 5) | (g << 3) | (u << 2) | v;
    vt[((long)(hh * KT + kt) * 32 + d) * 128 + s] = f2bf(kv[m * C_DIM + 128 + ch] + acc);
}

// ---------------------------------------------------------------------------
// Fused MFMA flash attention, both branches, NO-MAX softmax, SWAPPED-QK,
// FULLY IN-REGISTER SOFTMAX (zero LDS), TWO Q-GROUPS PER WAVE,
// double-buffered K and V prefetch (passing r18/r19 structure, unchanged).
// ---------------------------------------------------------------------------
__global__ __launch_bounds__(256, 2) void attn_fused_kernel(
    const unsigned short* __restrict__ qb,
    const unsigned short* __restrict__ kb1, const unsigned short* __restrict__ vt1,
    const unsigned short* __restrict__ kb2, const unsigned short* __restrict__ vt2,
    float* __restrict__ outcat) {
    int wave = threadIdx.x >> 6;
    int lane = threadIdx.x & 63;
    int lg = lane >> 4;
    int lc = lane & 15;
    int by = blockIdx.y;
    int big = ((by >> 2) == 0);  // by 0..3 = branch-2 (M=2048), dispatched first
    int head = by & 3;
    const unsigned short* kb = big ? kb2 : kb1;
    const unsigned short* vt = big ? vt2 : vt1;
    int KT = big ? 16 : 4;
    int col_base = big ? 128 : 0;
    int q0 = blockIdx.x * 128 + wave * 32;

    bf16x8 qf0 = *reinterpret_cast<const bf16x8*>(qb + (long)(q0 + lc) * C_DIM + col_base + head * HD + lg * 8);
    bf16x8 qf1 = *reinterpret_cast<const bf16x8*>(qb + (long)(q0 + 16 + lc) * C_DIM + col_base + head * HD + lg * 8);

    const unsigned short* kbase = kb + (long)head * KT * 4096;
    const unsigned short* vbase = vt + (long)head * KT * 4096;

    f32x4 o00 = {0.f, 0.f, 0.f, 0.f}, o01 = {0.f, 0.f, 0.f, 0.f};
    f32x4 o10 = {0.f, 0.f, 0.f, 0.f}, o11 = {0.f, 0.f, 0.f, 0.f};
    float lsum0 = 0.f, lsum1 = 0.f;

    bf16x8 kf[8];
    bf16x8 vf0c[4], vf1c[4];
#pragma unroll
    for (int c = 0; c < 8; ++c)
        kf[c] = *reinterpret_cast<const bf16x8*>(kbase + (16 * c + lc) * 32 + lg * 8);
#pragma unroll
    for (int c2 = 0; c2 < 4; ++c2) {
        vf0c[c2] = *reinterpret_cast<const bf16x8*>(vbase + lc * 128 + c2 * 32 + lg * 8);
        vf1c[c2] = *reinterpret_cast<const bf16x8*>(vbase + (16 + lc) * 128 + c2 * 32 + lg * 8);
    }

    for (int kt = 0; kt < KT; ++kt) {
        // QK^T swapped, both q-groups share kf: s*[c][r] = S[key=16c+4lg+r][query=lc]
        f32x4 s0[8], s1[8];
        f32x4 z = {0.f, 0.f, 0.f, 0.f};
#pragma unroll
        for (int c = 0; c < 8; ++c) {
            s0[c] = __builtin_amdgcn_mfma_f32_16x16x32_bf16(kf[c], qf0, z, 0, 0, 0);
            s1[c] = __builtin_amdgcn_mfma_f32_16x16x32_bf16(kf[c], qf1, z, 0, 0, 0);
        }
        // prefetch next tile's K (overwrite, consumed) AND V (separate bufs)
        bf16x8 vf0n[4], vf1n[4];
        if (kt + 1 < KT) {
            const unsigned short* knext = kbase + (long)(kt + 1) * 4096;
            const unsigned short* vnext = vbase + (long)(kt + 1) * 4096;
#pragma unroll
            for (int c = 0; c < 8; ++c)
                kf[c] = *reinterpret_cast<const bf16x8*>(knext + (16 * c + lc) * 32 + lg * 8);
#pragma unroll
            for (int c2 = 0; c2 < 4; ++c2) {
                vf0n[c2] = *reinterpret_cast<const bf16x8*>(vnext + lc * 128 + c2 * 32 + lg * 8);
                vf1n[c2] = *reinterpret_cast<const bf16x8*>(vnext + (16 + lc) * 128 + c2 * 32 + lg * 8);
            }
        }
        // in-register softmax + PV A-frag packing, group 0 then group 1
#pragma unroll
        for (int c2 = 0; c2 < 4; ++c2) {
            unsigned int w0, w1, w2, w3;
            {
                int c = 2 * c2;
                float p0 = __builtin_amdgcn_exp2f(s0[c][0]);
                float p1 = __builtin_amdgcn_exp2f(s0[c][1]);
                float p2 = __builtin_amdgcn_exp2f(s0[c][2]);
                float p3 = __builtin_amdgcn_exp2f(s0[c][3]);
                lsum0 += (p0 + p1) + (p2 + p3);
                w0 = cvtpk_bf16(p0, p1);
                w1 = cvtpk_bf16(p2, p3);
            }
            {
                int c = 2 * c2 + 1;
                float p0 = __builtin_amdgcn_exp2f(s0[c][0]);
                float p1 = __builtin_amdgcn_exp2f(s0[c][1]);
                float p2 = __builtin_amdgcn_exp2f(s0[c][2]);
                float p3 = __builtin_amdgcn_exp2f(s0[c][3]);
                lsum0 += (p0 + p1) + (p2 + p3);
                w2 = cvtpk_bf16(p0, p1);
                w3 = cvtpk_bf16(p2, p3);
            }
            u32x4 pw = {w0, w1, w2, w3};
            bf16x8 pa = __builtin_bit_cast(bf16x8, pw);
            o00 = __builtin_amdgcn_mfma_f32_16x16x32_bf16(pa, vf0c[c2], o00, 0, 0, 0);
            o01 = __builtin_amdgcn_mfma_f32_16x16x32_bf16(pa, vf1c[c2], o01, 0, 0, 0);
        }
#pragma unroll
        for (int c2 = 0; c2 < 4; ++c2) {
            unsigned int w0, w1, w2, w3;
            {
                int c = 2 * c2;
                float p0 = __builtin_amdgcn_exp2f(s1[c][0]);
                float p1 = __builtin_amdgcn_exp2f(s1[c][1]);
                float p2 = __builtin_amdgcn_exp2f(s1[c][2]);
                float p3 = __builtin_amdgcn_exp2f(s1[c][3]);
                lsum1 += (p0 + p1) + (p2 + p3);
                w0 = cvtpk_bf16(p0, p1);
                w1 = cvtpk_bf16(p2, p3);
            }
            {
                int c = 2 * c2 + 1;
                float p0 = __builtin_amdgcn_exp2f(s1[c][0]);
                float p1 = __builtin_amdgcn_exp2f(s1[c][1]);
                float p2 = __builtin_amdgcn_exp2f(s1[c][2]);
                float p3 = __builtin_amdgcn_exp2f(s1[c][3]);
                lsum1 += (p0 + p1) + (p2 + p3);
                w2 = cvtpk_bf16(p0, p1);
                w3 = cvtpk_bf16(p2, p3);
            }
            u32x4 pw = {w0, w1, w2, w3};
            bf16x8 pa = __builtin_bit_cast(bf16x8, pw);
            o10 = __builtin_amdgcn_mfma_f32_16x16x32_bf16(pa, vf0c[c2], o10, 0, 0, 0);
            o11 = __builtin_amdgcn_mfma_f32_16x16x32_bf16(pa, vf1c[c2], o11, 0, 0, 0);
        }
        if (kt + 1 < KT) {
#pragma unroll
            for (int c2 = 0; c2 < 4; ++c2) {
                vf0c[c2] = vf0n[c2];
                vf1c[c2] = vf1n[c2];
            }
        }
    }
    // reduce each group's lsum across the 4 lg-groups, then distribute
    lsum0 += __shfl_xor(lsum0, 16);
    lsum0 += __shfl_xor(lsum0, 32);
    lsum1 += __shfl_xor(lsum1, 16);
    lsum1 += __shfl_xor(lsum1, 32);
#pragma unroll
    for (int r = 0; r < 4; ++r) {
        float ls = __shfl(lsum0, lg * 4 + r);
        float inv = 1.f / ls;
        int row = q0 + lg * 4 + r;
        outcat[(long)row * C_DIM + col_base + head * HD + lc] = o00[r] * inv;
        outcat[(long)row * C_DIM + col_base + head * HD + 16 + lc] = o01[r] * inv;
    }
#pragma unroll
    for (int r = 0; r < 4; ++r) {
        float ls = __shfl(lsum1, lg * 4 + r);
        float inv = 1.f / ls;
        int row = q0 + 16 + lg * 4 + r;
        outcat[(long)row * C_DIM + col_base + head * HD + lc] = o10[r] * inv;
        outcat[(long)row * C_DIM + col_base + head * HD + 16 + lc] = o11[r] * inv;
    }
}

// ---------------------------------------------------------------------------
extern "C" void kernel_launch(void* const* d_in, const int* in_sizes, int n_in,
                              void* d_out, int out_size, void* d_ws, size_t ws_size,
                              hipStream_t stream) {
    const float* x      = (const float*)d_in[0];
    const float* Wq     = (const float*)d_in[1];
    const float* sr1_w  = (const float*)d_in[2];
    const float* sr1_b  = (const float*)d_in[3];
    const float* ln1_w  = (const float*)d_in[4];
    const float* ln1_b  = (const float*)d_in[5];
    const float* sr2_w  = (const float*)d_in[6];
    const float* sr2_b  = (const float*)d_in[7];
    const float* ln2_w  = (const float*)d_in[8];
    const float* ln2_b  = (const float*)d_in[9];
    const float* Wkv1   = (const float*)d_in[10];
    const float* Wkv2   = (const float*)d_in[11];
    const float* lc1_w  = (const float*)d_in[12];
    const float* lc1_b  = (const float*)d_in[13];
    const float* lc2_w  = (const float*)d_in[14];
    const float* lc2_b  = (const float*)d_in[15];
    const float* proj_w = (const float*)d_in[16];
    const float* proj_b = (const float*)d_in[17];
    float* out = (float*)d_out;
    char* wsb = (char*)d_ws;

    // workspace layout (fits in 27.5 MB; buf0 is triple-purposed SEQUENTIALLY:
    // sr1 partials -> sr2 partials (4 x 2 MB) -> cat)
    float* buf0 = (float*)wsb;                                  // 8 MB
    unsigned short* qb = (unsigned short*)(wsb + 8388608);      // 4 MB
    float* im = (float*)(wsb + 12582912);                       // 8 MB
    float* xr1 = (float*)(wsb + 20971520);
    float* kv1 = (float*)(wsb + 21495808);
    unsigned short* kb1 = (unsigned short*)(wsb + 22020096);
    unsigned short* vt1 = (unsigned short*)(wsb + 22151168);
    float* xr2 = (float*)(wsb + 22282240);
    float* kv2 = (float*)(wsb + 24379392);
    unsigned short* kb2 = (unsigned short*)(wsb + 26476544);
    unsigned short* vt2 = (unsigned short*)(wsb + 27000832);

    float* cat = buf0;
    float* part1 = buf0;   // 16 x 0.5 MB, dead after branch-1 reduce
    float* part2 = buf0;   // 4 x 2 MB, lives between sr2 GEMM and its reduce

    // q = bf16(scale * x @ Wq.T), fused epilogue
    gemm_split_kernel<<<dim3(4, 128, 1), 256, 0, stream>>>(x, Wq, nullptr, (float*)qb, 8192, 256, 256,
                                                           qb, nullptr, 0);

    // ---- branch 1 (stride 4): M = 512, K = 4096, split-K 16 ----
    im2col_kernel<4><<<512, 256, 0, stream>>>(x, im, 8);
    gemm_split_kernel<<<dim3(4, 8, 16), 256, 0, stream>>>(im, sr1_w, nullptr, part1, 512, 256, 4096,
                                                          nullptr, nullptr, 0);
    reduce_ln_gelu_kernel<<<512, 256, 0, stream>>>(part1, sr1_b, ln1_w, ln1_b, xr1, 512 * 256, 16);
    gemm_split_kernel<<<dim3(4, 8, 1), 256, 0, stream>>>(xr1, Wkv1, nullptr, kv1, 512, 256, 256,
                                                         nullptr, kb1, 4);
    dw_conv_kernel<<<512, 128, 0, stream>>>(kv1, lc1_w, lc1_b, vt1, 8, 8, 4);

    // ---- branch 2 (stride 2): M = 2048, K = 1024, split-K 4 (part2 in buf0) ----
    im2col_kernel<2><<<2048, 256, 0, stream>>>(x, im, 16);
    gemm_split_kernel<<<dim3(4, 32, 4), 256, 0, stream>>>(im, sr2_w, nullptr, part2, 2048, 256, 1024,
                                                          nullptr, nullptr, 0);
    reduce_ln_gelu_kernel<<<2048, 256, 0, stream>>>(part2, sr2_b, ln2_w, ln2_b, xr2, 2048 * 256, 4);
    gemm_split_kernel<<<dim3(4, 32, 1), 256, 0, stream>>>(xr2, Wkv2, nullptr, kv2, 2048, 256, 256,
                                                          nullptr, kb2, 16);
    dw_conv_kernel<<<2048, 128, 0, stream>>>(kv2, lc2_w, lc2_b, vt2, 16, 16, 16);

    // fused attention over both branches (4 waves / 128 q-rows per block)
    attn_fused_kernel<<<dim3(64, 8), 256, 0, stream>>>(qb, kb1, vt1, kb2, vt2, cat);

    // out = cat @ proj_w.T + proj_b
    gemm_split_kernel<<<dim3(4, 128, 1), 256, 0, stream>>>(cat, proj_w, proj_b, out, 8192, 256, 256,
                                                           nullptr, nullptr, 0);
}

// Round 21
// 121.490 us; speedup vs baseline: 1.0109x; 1.0109x over previous
//
#include <hip/hip_runtime.h>
#include <math.h>

#define C_DIM 256
#define HH 32
#define WW 32
#define ZZ 8
#define HD 32

typedef __attribute__((ext_vector_type(8))) short bf16x8;
typedef __attribute__((ext_vector_type(4))) float f32x4;
typedef __attribute__((ext_vector_type(4))) unsigned int u32x4;

__device__ inline unsigned short f2bf(float f) {
    unsigned int u = __builtin_bit_cast(unsigned int, f);
    u += 0x7FFF + ((u >> 16) & 1);
    return (unsigned short)(u >> 16);
}
__device__ inline float bf2f(unsigned short h) {
    unsigned int u = ((unsigned int)h) << 16;
    return __builtin_bit_cast(float, u);
}
__device__ inline unsigned int cvtpk_bf16(float a, float b) {
    unsigned int r;
    asm("v_cvt_pk_bf16_f32 %0, %1, %2" : "=v"(r) : "v"(a), "v"(b));
    return r;  // lo = bf16(a), hi = bf16(b)
}

// softmax scale with log2(e) folded in: exp2(q*k*QSCALE) == exp(q*k/sqrt(32))
#define QSCALE (0.17677669529663689f * 1.4426950408889634f)

// ---------------------------------------------------------------------------
// Split-bf16 MFMA GEMM with split-K, double-buffered LDS + reg prefetch.
// C[i,j] = sum_k A[i,k]*B[j,k] (+bias[j] if gridDim.z==1 && bias)
// hi/lo split via v_cvt_pk_bf16_f32 (exact residual by Sterbenz).
// Epilogue: qb_out != null -> write f2bf(val*QSCALE) to qb_out; skip C.
// ---------------------------------------------------------------------------
__global__ __launch_bounds__(256) void gemm_split_kernel(
    const float* __restrict__ A, const float* __restrict__ B,
    const float* __restrict__ bias, float* __restrict__ C,
    int M, int N, int K,
    unsigned short* __restrict__ qb_out) {
    __shared__ unsigned short Ah[2][2560], Al[2][2560], Bh[2][2560], Bl[2][2560];
    int t = threadIdx.x;
    int wave = t >> 6, lane = t & 63;
    int lg = lane >> 4, lc = lane & 15;
    int wm = wave >> 1, wn = wave & 1;
    int m0 = blockIdx.y * 64, n0 = blockIdx.x * 64;
    int Kc = K / gridDim.z;
    int kbeg = blockIdx.z * Kc;
    float* Cz = C + (long)blockIdx.z * M * N;
    int srow = t >> 2, sc8 = (t & 3) * 8;
    const float* aBase = A + (long)(m0 + srow) * K + kbeg + sc8;
    const float* bBase = B + (long)(n0 + srow) * K + kbeg + sc8;
    int nIter = Kc / 32;

    f32x4 acc[2][2];
#pragma unroll
    for (int i = 0; i < 2; ++i)
#pragma unroll
        for (int j = 0; j < 2; ++j) acc[i][j] = (f32x4){0.f, 0.f, 0.f, 0.f};

    auto split8 = [](f32x4 v0, f32x4 v1, u32x4& hw, u32x4& lw) {
        float av[8] = {v0[0], v0[1], v0[2], v0[3], v1[0], v1[1], v1[2], v1[3]};
#pragma unroll
        for (int p = 0; p < 4; ++p) {
            float x0 = av[2 * p], x1 = av[2 * p + 1];
            unsigned int w = cvtpk_bf16(x0, x1);
            float h0 = __builtin_bit_cast(float, w << 16);
            float h1 = __builtin_bit_cast(float, w & 0xFFFF0000u);
            hw[p] = w;
            lw[p] = cvtpk_bf16(x0 - h0, x1 - h1);
        }
    };
    auto cvt_store = [&](int buf, f32x4 a0, f32x4 a1, f32x4 b0, f32x4 b1) {
        u32x4 hw, lw;
        split8(a0, a1, hw, lw);
        *reinterpret_cast<u32x4*>(&Ah[buf][srow * 40 + sc8]) = hw;
        *reinterpret_cast<u32x4*>(&Al[buf][srow * 40 + sc8]) = lw;
        split8(b0, b1, hw, lw);
        *reinterpret_cast<u32x4*>(&Bh[buf][srow * 40 + sc8]) = hw;
        *reinterpret_cast<u32x4*>(&Bl[buf][srow * 40 + sc8]) = lw;
    };

    {
        f32x4 a0 = *reinterpret_cast<const f32x4*>(aBase);
        f32x4 a1 = *reinterpret_cast<const f32x4*>(aBase + 4);
        f32x4 b0 = *reinterpret_cast<const f32x4*>(bBase);
        f32x4 b1 = *reinterpret_cast<const f32x4*>(bBase + 4);
        cvt_store(0, a0, a1, b0, b1);
    }
    __syncthreads();

    for (int k = 0; k < nIter; ++k) {
        int cur = k & 1;
        bool more = (k + 1 < nIter);
        f32x4 na0, na1, nb0, nb1;
        if (more) {
            const float* ap = aBase + (k + 1) * 32;
            const float* bp = bBase + (k + 1) * 32;
            na0 = *reinterpret_cast<const f32x4*>(ap);
            na1 = *reinterpret_cast<const f32x4*>(ap + 4);
            nb0 = *reinterpret_cast<const f32x4*>(bp);
            nb1 = *reinterpret_cast<const f32x4*>(bp + 4);
        }
        bf16x8 afh[2], afl[2], bfh[2], bfl[2];
#pragma unroll
        for (int i = 0; i < 2; ++i) {
            int ar = wm * 32 + i * 16 + lc;
            afh[i] = *reinterpret_cast<const bf16x8*>(&Ah[cur][ar * 40 + lg * 8]);
            afl[i] = *reinterpret_cast<const bf16x8*>(&Al[cur][ar * 40 + lg * 8]);
            int br = wn * 32 + i * 16 + lc;
            bfh[i] = *reinterpret_cast<const bf16x8*>(&Bh[cur][br * 40 + lg * 8]);
            bfl[i] = *reinterpret_cast<const bf16x8*>(&Bl[cur][br * 40 + lg * 8]);
        }
#pragma unroll
        for (int i = 0; i < 2; ++i)
#pragma unroll
            for (int j = 0; j < 2; ++j) {
                acc[i][j] = __builtin_amdgcn_mfma_f32_16x16x32_bf16(afh[i], bfh[j], acc[i][j], 0, 0, 0);
                acc[i][j] = __builtin_amdgcn_mfma_f32_16x16x32_bf16(afh[i], bfl[j], acc[i][j], 0, 0, 0);
                acc[i][j] = __builtin_amdgcn_mfma_f32_16x16x32_bf16(afl[i], bfh[j], acc[i][j], 0, 0, 0);
            }
        if (more) {
            cvt_store(cur ^ 1, na0, na1, nb0, nb1);
            __syncthreads();
        }
    }
#pragma unroll
    for (int i = 0; i < 2; ++i)
#pragma unroll
        for (int j = 0; j < 2; ++j)
#pragma unroll
            for (int r = 0; r < 4; ++r) {
                int row = m0 + wm * 32 + i * 16 + lg * 4 + r;
                int col = n0 + wn * 32 + j * 16 + lc;
                float bv = bias ? bias[col] : 0.f;
                float val = acc[i][j][r] + bv;
                if (qb_out) {
                    qb_out[(long)row * N + col] = f2bf(val * QSCALE);
                } else {
                    Cz[(long)row * N + col] = val;
                }
            }
}

// ---------------------------------------------------------------------------
// Fused: sum KS split-K planes + bias, then LayerNorm + exact GELU.
// ---------------------------------------------------------------------------
__global__ void reduce_ln_gelu_kernel(const float* __restrict__ part,
                                      const float* __restrict__ bias,
                                      const float* __restrict__ g,
                                      const float* __restrict__ bb,
                                      float* __restrict__ xr, int MN, int KS) {
    int m = blockIdx.x;
    int c = threadIdx.x;
    float v = bias[c];
    for (int z = 0; z < KS; ++z) v += part[(long)z * MN + m * C_DIM + c];
    __shared__ float wred[4];
    float s = v;
    for (int off = 32; off; off >>= 1) s += __shfl_down(s, off);
    if ((c & 63) == 0) wred[c >> 6] = s;
    __syncthreads();
    float mean = (wred[0] + wred[1] + wred[2] + wred[3]) * (1.f / 256.f);
    __syncthreads();
    float d = v - mean;
    float s2 = d * d;
    for (int off = 32; off; off >>= 1) s2 += __shfl_down(s2, off);
    if ((c & 63) == 0) wred[c >> 6] = s2;
    __syncthreads();
    float var = (wred[0] + wred[1] + wred[2] + wred[3]) * (1.f / 256.f);
    float y = d * rsqrtf(var + 1e-5f) * g[c] + bb[c];
    float ge = 0.5f * y * (1.f + erff(y * 0.70710678118654752f));
    xr[m * C_DIM + c] = ge;
}

// ---------------------------------------------------------------------------
// Sum KS split-K planes for a kv GEMM; write f32 kv AND (cols<128) the tiled
// bf16 K buffer: kb[((h*KTp+kt)*128+mi)*32+c] (same formula as the old GEMM
// epilogue, verified passing r12-r20).
// ---------------------------------------------------------------------------
__global__ void reduce_kv_kernel(const float* __restrict__ part,
                                 float* __restrict__ kv,
                                 unsigned short* __restrict__ kb,
                                 int MN, int KS, int KTp) {
    int m = blockIdx.x;
    int c = threadIdx.x;
    float v = 0.f;
    for (int z = 0; z < KS; ++z) v += part[(long)z * MN + m * C_DIM + c];
    kv[m * C_DIM + c] = v;
    if (c < 128) {
        int h = c >> 5, cc = c & 31, kt = m >> 7, mi = m & 127;
        kb[((long)(h * KTp + kt) * 128 + mi) * 32 + cc] = f2bf(v);
    }
}

// ---------------------------------------------------------------------------
// im2col for SR conv.
// ---------------------------------------------------------------------------
template <int S>
__global__ void im2col_kernel(const float* __restrict__ x, float* __restrict__ im, int Ws) {
    constexpr int T = S * S;
    __shared__ float patch[T * 257];
    int m = blockIdx.x;
    int z = m % ZZ;
    int wo = (m / ZZ) % Ws;
    int ho = m / (ZZ * Ws);
    int t = threadIdx.x;
#pragma unroll
    for (int tap = 0; tap < T; ++tap) {
        int kh = tap / S, kw = tap % S;
        int row = (ho * S + kh) * (WW * ZZ) + (wo * S + kw) * ZZ + z;
        patch[tap * 257 + t] = x[row * C_DIM + t];
    }
    __syncthreads();
#pragma unroll
    for (int rep = 0; rep < T; ++rep) {
        int k = rep * 256 + t;
        int ci = k / T, tap = k % T;
        im[(long)m * (256 * T) + k] = patch[tap * 257 + ci];
    }
}

// ---------------------------------------------------------------------------
// Fused depthwise 3x3x1 conv on V + residual for BOTH branches.
// blockIdx.x < 512: branch 1 (Ws=Hs=8, KT=4); else branch 2 (m-512, 16,16,16).
// Writes tiled V^T bf16 with the swapped-QK slot permutation:
// mi = a<<5|u<<4|g<<2|v -> s = a<<5|g<<3|u<<2|v.
// ---------------------------------------------------------------------------
__global__ void dw_conv_fused_kernel(const float* __restrict__ kv1, const float* __restrict__ lw1,
                                     const float* __restrict__ lb1, unsigned short* __restrict__ vt1,
                                     const float* __restrict__ kv2, const float* __restrict__ lw2,
                                     const float* __restrict__ lb2, unsigned short* __restrict__ vt2) {
    int bx = blockIdx.x;
    int b1 = (bx < 512);
    int m = b1 ? bx : bx - 512;
    const float* kv = b1 ? kv1 : kv2;
    const float* lw = b1 ? lw1 : lw2;
    const float* lb = b1 ? lb1 : lb2;
    unsigned short* vt = b1 ? vt1 : vt2;
    int Ws = b1 ? 8 : 16, Hs = b1 ? 8 : 16, KT = b1 ? 4 : 16;

    int ch = threadIdx.x;
    int z = m % ZZ;
    int wo = (m / ZZ) % Ws;
    int ho = m / (ZZ * Ws);
    float acc = lb[ch];
#pragma unroll
    for (int kh = 0; kh < 3; ++kh) {
        int h = ho + kh - 1;
        if (h < 0 || h >= Hs) continue;
#pragma unroll
        for (int kw = 0; kw < 3; ++kw) {
            int w2 = wo + kw - 1;
            if (w2 < 0 || w2 >= Ws) continue;
            int mm = (h * Ws + w2) * ZZ + z;
            acc += kv[mm * C_DIM + 128 + ch] * lw[ch * 9 + kh * 3 + kw];
        }
    }
    int hh = ch >> 5, d = ch & 31, kt = m >> 7, mi = m & 127;
    int a = mi >> 5, u = (mi >> 4) & 1, g = (mi >> 2) & 3, v = mi & 3;
    int s = (a << 5) | (g << 3) | (u << 2) | v;
    vt[((long)(hh * KT + kt) * 32 + d) * 128 + s] = f2bf(kv[m * C_DIM + 128 + ch] + acc);
}

// ---------------------------------------------------------------------------
// Fused MFMA flash attention, both branches, NO-MAX softmax, SWAPPED-QK,
// FULLY IN-REGISTER SOFTMAX (zero LDS), TWO Q-GROUPS PER WAVE,
// double-buffered K and V prefetch (passing r18-r20 structure, unchanged).
// ---------------------------------------------------------------------------
__global__ __launch_bounds__(256, 2) void attn_fused_kernel(
    const unsigned short* __restrict__ qb,
    const unsigned short* __restrict__ kb1, const unsigned short* __restrict__ vt1,
    const unsigned short* __restrict__ kb2, const unsigned short* __restrict__ vt2,
    float* __restrict__ outcat) {
    int wave = threadIdx.x >> 6;
    int lane = threadIdx.x & 63;
    int lg = lane >> 4;
    int lc = lane & 15;
    int by = blockIdx.y;
    int big = ((by >> 2) == 0);  // by 0..3 = branch-2 (M=2048), dispatched first
    int head = by & 3;
    const unsigned short* kb = big ? kb2 : kb1;
    const unsigned short* vt = big ? vt2 : vt1;
    int KT = big ? 16 : 4;
    int col_base = big ? 128 : 0;
    int q0 = blockIdx.x * 128 + wave * 32;

    bf16x8 qf0 = *reinterpret_cast<const bf16x8*>(qb + (long)(q0 + lc) * C_DIM + col_base + head * HD + lg * 8);
    bf16x8 qf1 = *reinterpret_cast<const bf16x8*>(qb + (long)(q0 + 16 + lc) * C_DIM + col_base + head * HD + lg * 8);

    const unsigned short* kbase = kb + (long)head * KT * 4096;
    const unsigned short* vbase = vt + (long)head * KT * 4096;

    f32x4 o00 = {0.f, 0.f, 0.f, 0.f}, o01 = {0.f, 0.f, 0.f, 0.f};
    f32x4 o10 = {0.f, 0.f, 0.f, 0.f}, o11 = {0.f, 0.f, 0.f, 0.f};
    float lsum0 = 0.f, lsum1 = 0.f;

    bf16x8 kf[8];
    bf16x8 vf0c[4], vf1c[4];
#pragma unroll
    for (int c = 0; c < 8; ++c)
        kf[c] = *reinterpret_cast<const bf16x8*>(kbase + (16 * c + lc) * 32 + lg * 8);
#pragma unroll
    for (int c2 = 0; c2 < 4; ++c2) {
        vf0c[c2] = *reinterpret_cast<const bf16x8*>(vbase + lc * 128 + c2 * 32 + lg * 8);
        vf1c[c2] = *reinterpret_cast<const bf16x8*>(vbase + (16 + lc) * 128 + c2 * 32 + lg * 8);
    }

    for (int kt = 0; kt < KT; ++kt) {
        // QK^T swapped, both q-groups share kf: s*[c][r] = S[key=16c+4lg+r][query=lc]
        f32x4 s0[8], s1[8];
        f32x4 z = {0.f, 0.f, 0.f, 0.f};
#pragma unroll
        for (int c = 0; c < 8; ++c) {
            s0[c] = __builtin_amdgcn_mfma_f32_16x16x32_bf16(kf[c], qf0, z, 0, 0, 0);
            s1[c] = __builtin_amdgcn_mfma_f32_16x16x32_bf16(kf[c], qf1, z, 0, 0, 0);
        }
        // prefetch next tile's K (overwrite, consumed) AND V (separate bufs)
        bf16x8 vf0n[4], vf1n[4];
        if (kt + 1 < KT) {
            const unsigned short* knext = kbase + (long)(kt + 1) * 4096;
            const unsigned short* vnext = vbase + (long)(kt + 1) * 4096;
#pragma unroll
            for (int c = 0; c < 8; ++c)
                kf[c] = *reinterpret_cast<const bf16x8*>(knext + (16 * c + lc) * 32 + lg * 8);
#pragma unroll
            for (int c2 = 0; c2 < 4; ++c2) {
                vf0n[c2] = *reinterpret_cast<const bf16x8*>(vnext + lc * 128 + c2 * 32 + lg * 8);
                vf1n[c2] = *reinterpret_cast<const bf16x8*>(vnext + (16 + lc) * 128 + c2 * 32 + lg * 8);
            }
        }
        // in-register softmax + PV A-frag packing, group 0 then group 1
#pragma unroll
        for (int c2 = 0; c2 < 4; ++c2) {
            unsigned int w0, w1, w2, w3;
            {
                int c = 2 * c2;
                float p0 = __builtin_amdgcn_exp2f(s0[c][0]);
                float p1 = __builtin_amdgcn_exp2f(s0[c][1]);
                float p2 = __builtin_amdgcn_exp2f(s0[c][2]);
                float p3 = __builtin_amdgcn_exp2f(s0[c][3]);
                lsum0 += (p0 + p1) + (p2 + p3);
                w0 = cvtpk_bf16(p0, p1);
                w1 = cvtpk_bf16(p2, p3);
            }
            {
                int c = 2 * c2 + 1;
                float p0 = __builtin_amdgcn_exp2f(s0[c][0]);
                float p1 = __builtin_amdgcn_exp2f(s0[c][1]);
                float p2 = __builtin_amdgcn_exp2f(s0[c][2]);
                float p3 = __builtin_amdgcn_exp2f(s0[c][3]);
                lsum0 += (p0 + p1) + (p2 + p3);
                w2 = cvtpk_bf16(p0, p1);
                w3 = cvtpk_bf16(p2, p3);
            }
            u32x4 pw = {w0, w1, w2, w3};
            bf16x8 pa = __builtin_bit_cast(bf16x8, pw);
            o00 = __builtin_amdgcn_mfma_f32_16x16x32_bf16(pa, vf0c[c2], o00, 0, 0, 0);
            o01 = __builtin_amdgcn_mfma_f32_16x16x32_bf16(pa, vf1c[c2], o01, 0, 0, 0);
        }
#pragma unroll
        for (int c2 = 0; c2 < 4; ++c2) {
            unsigned int w0, w1, w2, w3;
            {
                int c = 2 * c2;
                float p0 = __builtin_amdgcn_exp2f(s1[c][0]);
                float p1 = __builtin_amdgcn_exp2f(s1[c][1]);
                float p2 = __builtin_amdgcn_exp2f(s1[c][2]);
                float p3 = __builtin_amdgcn_exp2f(s1[c][3]);
                lsum1 += (p0 + p1) + (p2 + p3);
                w0 = cvtpk_bf16(p0, p1);
                w1 = cvtpk_bf16(p2, p3);
            }
            {
                int c = 2 * c2 + 1;
                float p0 = __builtin_amdgcn_exp2f(s1[c][0]);
                float p1 = __builtin_amdgcn_exp2f(s1[c][1]);
                float p2 = __builtin_amdgcn_exp2f(s1[c][2]);
                float p3 = __builtin_amdgcn_exp2f(s1[c][3]);
                lsum1 += (p0 + p1) + (p2 + p3);
                w2 = cvtpk_bf16(p0, p1);
                w3 = cvtpk_bf16(p2, p3);
            }
            u32x4 pw = {w0, w1, w2, w3};
            bf16x8 pa = __builtin_bit_cast(bf16x8, pw);
            o10 = __builtin_amdgcn_mfma_f32_16x16x32_bf16(pa, vf0c[c2], o10, 0, 0, 0);
            o11 = __builtin_amdgcn_mfma_f32_16x16x32_bf16(pa, vf1c[c2], o11, 0, 0, 0);
        }
        if (kt + 1 < KT) {
#pragma unroll
            for (int c2 = 0; c2 < 4; ++c2) {
                vf0c[c2] = vf0n[c2];
                vf1c[c2] = vf1n[c2];
            }
        }
    }
    // reduce each group's lsum across the 4 lg-groups, then distribute
    lsum0 += __shfl_xor(lsum0, 16);
    lsum0 += __shfl_xor(lsum0, 32);
    lsum1 += __shfl_xor(lsum1, 16);
    lsum1 += __shfl_xor(lsum1, 32);
#pragma unroll
    for (int r = 0; r < 4; ++r) {
        float ls = __shfl(lsum0, lg * 4 + r);
        float inv = 1.f / ls;
        int row = q0 + lg * 4 + r;
        outcat[(long)row * C_DIM + col_base + head * HD + lc] = o00[r] * inv;
        outcat[(long)row * C_DIM + col_base + head * HD + 16 + lc] = o01[r] * inv;
    }
#pragma unroll
    for (int r = 0; r < 4; ++r) {
        float ls = __shfl(lsum1, lg * 4 + r);
        float inv = 1.f / ls;
        int row = q0 + 16 + lg * 4 + r;
        outcat[(long)row * C_DIM + col_base + head * HD + lc] = o10[r] * inv;
        outcat[(long)row * C_DIM + col_base + head * HD + 16 + lc] = o11[r] * inv;
    }
}

// ---------------------------------------------------------------------------
extern "C" void kernel_launch(void* const* d_in, const int* in_sizes, int n_in,
                              void* d_out, int out_size, void* d_ws, size_t ws_size,
                              hipStream_t stream) {
    const float* x      = (const float*)d_in[0];
    const float* Wq     = (const float*)d_in[1];
    const float* sr1_w  = (const float*)d_in[2];
    const float* sr1_b  = (const float*)d_in[3];
    const float* ln1_w  = (const float*)d_in[4];
    const float* ln1_b  = (const float*)d_in[5];
    const float* sr2_w  = (const float*)d_in[6];
    const float* sr2_b  = (const float*)d_in[7];
    const float* ln2_w  = (const float*)d_in[8];
    const float* ln2_b  = (const float*)d_in[9];
    const float* Wkv1   = (const float*)d_in[10];
    const float* Wkv2   = (const float*)d_in[11];
    const float* lc1_w  = (const float*)d_in[12];
    const float* lc1_b  = (const float*)d_in[13];
    const float* lc2_w  = (const float*)d_in[14];
    const float* lc2_b  = (const float*)d_in[15];
    const float* proj_w = (const float*)d_in[16];
    const float* proj_b = (const float*)d_in[17];
    float* out = (float*)d_out;
    char* wsb = (char*)d_ws;

    // workspace layout (27.5 MB peak). buf0 sequentially: sr1 partials ->
    // sr2 partials -> cat. im sequentially: im2col data -> kv split-K partials.
    float* buf0 = (float*)wsb;                                  // 8 MB
    unsigned short* qb = (unsigned short*)(wsb + 8388608);      // 4 MB
    float* im = (float*)(wsb + 12582912);                       // 8 MB
    float* xr1 = (float*)(wsb + 20971520);
    float* kv1 = (float*)(wsb + 21495808);
    unsigned short* kb1 = (unsigned short*)(wsb + 22020096);
    unsigned short* vt1 = (unsigned short*)(wsb + 22151168);
    float* xr2 = (float*)(wsb + 22282240);
    float* kv2 = (float*)(wsb + 24379392);
    unsigned short* kb2 = (unsigned short*)(wsb + 26476544);
    unsigned short* vt2 = (unsigned short*)(wsb + 27000832);

    float* cat = buf0;
    float* part1 = buf0;    // 16 x 0.5 MB
    float* part2 = buf0;    // 4 x 2 MB
    float* kvpart = im;     // kv1: 8 x 0.5 MB; kv2: 4 x 2 MB (im dead by then)

    // q = bf16(scale * x @ Wq.T), fused epilogue
    gemm_split_kernel<<<dim3(4, 128, 1), 256, 0, stream>>>(x, Wq, nullptr, (float*)qb, 8192, 256, 256, qb);

    // ---- SR conv + LN/GELU for both branches (im in im2col role) ----
    im2col_kernel<4><<<512, 256, 0, stream>>>(x, im, 8);
    gemm_split_kernel<<<dim3(4, 8, 16), 256, 0, stream>>>(im, sr1_w, nullptr, part1, 512, 256, 4096, nullptr);
    reduce_ln_gelu_kernel<<<512, 256, 0, stream>>>(part1, sr1_b, ln1_w, ln1_b, xr1, 512 * 256, 16);
    im2col_kernel<2><<<2048, 256, 0, stream>>>(x, im, 16);
    gemm_split_kernel<<<dim3(4, 32, 4), 256, 0, stream>>>(im, sr2_w, nullptr, part2, 2048, 256, 1024, nullptr);
    reduce_ln_gelu_kernel<<<2048, 256, 0, stream>>>(part2, sr2_b, ln2_w, ln2_b, xr2, 2048 * 256, 4);

    // ---- kv GEMMs with split-K (partials in im, now dead) ----
    gemm_split_kernel<<<dim3(4, 8, 8), 256, 0, stream>>>(xr1, Wkv1, nullptr, kvpart, 512, 256, 256, nullptr);
    reduce_kv_kernel<<<512, 256, 0, stream>>>(kvpart, kv1, kb1, 512 * 256, 8, 4);
    gemm_split_kernel<<<dim3(4, 32, 4), 256, 0, stream>>>(xr2, Wkv2, nullptr, kvpart, 2048, 256, 256, nullptr);
    reduce_kv_kernel<<<2048, 256, 0, stream>>>(kvpart, kv2, kb2, 2048 * 256, 4, 16);

    // ---- fused depthwise conv (both branches, one launch) ----
    dw_conv_fused_kernel<<<2560, 128, 0, stream>>>(kv1, lc1_w, lc1_b, vt1, kv2, lc2_w, lc2_b, vt2);

    // fused attention over both branches (4 waves / 128 q-rows per block)
    attn_fused_kernel<<<dim3(64, 8), 256, 0, stream>>>(qb, kb1, vt1, kb2, vt2, cat);

    // out = cat @ proj_w.T + proj_b
    gemm_split_kernel<<<dim3(4, 128, 1), 256, 0, stream>>>(cat, proj_w, proj_b, out, 8192, 256, 256, nullptr);
}

// Round 22
// 118.961 us; speedup vs baseline: 1.0324x; 1.0213x over previous
//
#include <hip/hip_runtime.h>
#include <math.h>

#define C_DIM 256
#define HH 32
#define WW 32
#define ZZ 8
#define HD 32

typedef __attribute__((ext_vector_type(8))) short bf16x8;
typedef __attribute__((ext_vector_type(4))) float f32x4;
typedef __attribute__((ext_vector_type(4))) unsigned int u32x4;

__device__ inline unsigned short f2bf(float f) {
    unsigned int u = __builtin_bit_cast(unsigned int, f);
    u += 0x7FFF + ((u >> 16) & 1);
    return (unsigned short)(u >> 16);
}
__device__ inline unsigned int cvtpk_bf16(float a, float b) {
    unsigned int r;
    asm("v_cvt_pk_bf16_f32 %0, %1, %2" : "=v"(r) : "v"(a), "v"(b));
    return r;  // lo = bf16(a), hi = bf16(b)
}

// softmax scale with log2(e) folded in: exp2(q*k*QSCALE) == exp(q*k/sqrt(32))
#define QSCALE (0.17677669529663689f * 1.4426950408889634f)

// ---------------------------------------------------------------------------
// Split-bf16 MFMA GEMM with split-K, double-buffered LDS + reg prefetch.
// C[i,j] = sum_k A[i,k]*B[j,k] (+bias[j] if gridDim.z==1 && bias)
// ABF16=false: A is f32, split hi/lo via v_cvt_pk_bf16_f32 (exact residual),
//              3 MFMAs per (i,j): AhBh + AhBl + AlBh.
// ABF16=true:  A is bf16 (exact), no A-split, 2 MFMAs: A·Bh + A·Bl.
// Epilogue: qb_out != null -> write f2bf(val*QSCALE) to qb_out; skip C.
// ---------------------------------------------------------------------------
template <bool ABF16>
__global__ __launch_bounds__(256) void gemm_split_kernel(
    const void* __restrict__ Av, const float* __restrict__ B,
    const float* __restrict__ bias, float* __restrict__ C,
    int M, int N, int K,
    unsigned short* __restrict__ qb_out) {
    __shared__ unsigned short Ah[2][2560], Al[2][2560], Bh[2][2560], Bl[2][2560];
    int t = threadIdx.x;
    int wave = t >> 6, lane = t & 63;
    int lg = lane >> 4, lc = lane & 15;
    int wm = wave >> 1, wn = wave & 1;
    int m0 = blockIdx.y * 64, n0 = blockIdx.x * 64;
    int Kc = K / gridDim.z;
    int kbeg = blockIdx.z * Kc;
    float* Cz = C + (long)blockIdx.z * M * N;
    int srow = t >> 2, sc8 = (t & 3) * 8;
    const float* aBaseF = ABF16 ? nullptr : (const float*)Av + (long)(m0 + srow) * K + kbeg + sc8;
    const unsigned short* aBaseH = ABF16 ? (const unsigned short*)Av + (long)(m0 + srow) * K + kbeg + sc8 : nullptr;
    const float* bBase = B + (long)(n0 + srow) * K + kbeg + sc8;
    int nIter = Kc / 32;

    f32x4 acc[2][2];
#pragma unroll
    for (int i = 0; i < 2; ++i)
#pragma unroll
        for (int j = 0; j < 2; ++j) acc[i][j] = (f32x4){0.f, 0.f, 0.f, 0.f};

    auto split8 = [](f32x4 v0, f32x4 v1, u32x4& hw, u32x4& lw) {
        float av[8] = {v0[0], v0[1], v0[2], v0[3], v1[0], v1[1], v1[2], v1[3]};
#pragma unroll
        for (int p = 0; p < 4; ++p) {
            float x0 = av[2 * p], x1 = av[2 * p + 1];
            unsigned int w = cvtpk_bf16(x0, x1);
            float h0 = __builtin_bit_cast(float, w << 16);
            float h1 = __builtin_bit_cast(float, w & 0xFFFF0000u);
            hw[p] = w;
            lw[p] = cvtpk_bf16(x0 - h0, x1 - h1);
        }
    };

    // stage tile k0 into buffer buf
    auto stage = [&](int buf, int k) {
        if constexpr (ABF16) {
            u32x4 aw = *reinterpret_cast<const u32x4*>(aBaseH + k * 32);
            *reinterpret_cast<u32x4*>(&Ah[buf][srow * 40 + sc8]) = aw;
        } else {
            f32x4 a0 = *reinterpret_cast<const f32x4*>(aBaseF + k * 32);
            f32x4 a1 = *reinterpret_cast<const f32x4*>(aBaseF + k * 32 + 4);
            u32x4 hw, lw;
            split8(a0, a1, hw, lw);
            *reinterpret_cast<u32x4*>(&Ah[buf][srow * 40 + sc8]) = hw;
            *reinterpret_cast<u32x4*>(&Al[buf][srow * 40 + sc8]) = lw;
        }
        f32x4 b0 = *reinterpret_cast<const f32x4*>(bBase + k * 32);
        f32x4 b1 = *reinterpret_cast<const f32x4*>(bBase + k * 32 + 4);
        u32x4 hw, lw;
        split8(b0, b1, hw, lw);
        *reinterpret_cast<u32x4*>(&Bh[buf][srow * 40 + sc8]) = hw;
        *reinterpret_cast<u32x4*>(&Bl[buf][srow * 40 + sc8]) = lw;
    };

    stage(0, 0);
    __syncthreads();

    for (int k = 0; k < nIter; ++k) {
        int cur = k & 1;
        bool more = (k + 1 < nIter);
        bf16x8 afh[2], afl[2], bfh[2], bfl[2];
#pragma unroll
        for (int i = 0; i < 2; ++i) {
            int ar = wm * 32 + i * 16 + lc;
            afh[i] = *reinterpret_cast<const bf16x8*>(&Ah[cur][ar * 40 + lg * 8]);
            if constexpr (!ABF16)
                afl[i] = *reinterpret_cast<const bf16x8*>(&Al[cur][ar * 40 + lg * 8]);
            int br = wn * 32 + i * 16 + lc;
            bfh[i] = *reinterpret_cast<const bf16x8*>(&Bh[cur][br * 40 + lg * 8]);
            bfl[i] = *reinterpret_cast<const bf16x8*>(&Bl[cur][br * 40 + lg * 8]);
        }
#pragma unroll
        for (int i = 0; i < 2; ++i)
#pragma unroll
            for (int j = 0; j < 2; ++j) {
                acc[i][j] = __builtin_amdgcn_mfma_f32_16x16x32_bf16(afh[i], bfh[j], acc[i][j], 0, 0, 0);
                acc[i][j] = __builtin_amdgcn_mfma_f32_16x16x32_bf16(afh[i], bfl[j], acc[i][j], 0, 0, 0);
                if constexpr (!ABF16)
                    acc[i][j] = __builtin_amdgcn_mfma_f32_16x16x32_bf16(afl[i], bfh[j], acc[i][j], 0, 0, 0);
            }
        if (more) {
            stage(cur ^ 1, k + 1);
            __syncthreads();
        }
    }
#pragma unroll
    for (int i = 0; i < 2; ++i)
#pragma unroll
        for (int j = 0; j < 2; ++j)
#pragma unroll
            for (int r = 0; r < 4; ++r) {
                int row = m0 + wm * 32 + i * 16 + lg * 4 + r;
                int col = n0 + wn * 32 + j * 16 + lc;
                float bv = bias ? bias[col] : 0.f;
                float val = acc[i][j][r] + bv;
                if (qb_out) {
                    qb_out[(long)row * N + col] = f2bf(val * QSCALE);
                } else {
                    Cz[(long)row * N + col] = val;
                }
            }
}

// ---------------------------------------------------------------------------
// Fused (both branches): sum split-K planes + bias, LayerNorm + exact GELU.
// blocks 0..511 -> branch1 (KS=16); 512..2559 -> branch2 (KS=4).
// ---------------------------------------------------------------------------
__global__ void reduce_ln_gelu_fused_kernel(
    const float* __restrict__ p1, const float* __restrict__ b1f,
    const float* __restrict__ g1, const float* __restrict__ bb1, float* __restrict__ x1,
    const float* __restrict__ p2, const float* __restrict__ b2f,
    const float* __restrict__ g2, const float* __restrict__ bb2, float* __restrict__ x2) {
    int bx = blockIdx.x;
    int br1 = (bx < 512);
    int m = br1 ? bx : bx - 512;
    const float* part = br1 ? p1 : p2;
    const float* bias = br1 ? b1f : b2f;
    const float* g = br1 ? g1 : g2;
    const float* bb = br1 ? bb1 : bb2;
    float* xr = br1 ? x1 : x2;
    int MN = br1 ? 512 * 256 : 2048 * 256;
    int KS = br1 ? 16 : 4;

    int c = threadIdx.x;
    float v = bias[c];
    for (int z = 0; z < KS; ++z) v += part[(long)z * MN + m * C_DIM + c];
    __shared__ float wred[4];
    float s = v;
    for (int off = 32; off; off >>= 1) s += __shfl_down(s, off);
    if ((c & 63) == 0) wred[c >> 6] = s;
    __syncthreads();
    float mean = (wred[0] + wred[1] + wred[2] + wred[3]) * (1.f / 256.f);
    __syncthreads();
    float d = v - mean;
    float s2 = d * d;
    for (int off = 32; off; off >>= 1) s2 += __shfl_down(s2, off);
    if ((c & 63) == 0) wred[c >> 6] = s2;
    __syncthreads();
    float var = (wred[0] + wred[1] + wred[2] + wred[3]) * (1.f / 256.f);
    float y = d * rsqrtf(var + 1e-5f) * g[c] + bb[c];
    float ge = 0.5f * y * (1.f + erff(y * 0.70710678118654752f));
    xr[m * C_DIM + c] = ge;
}

// ---------------------------------------------------------------------------
// Fused (both branches): sum split-K planes for the kv GEMMs; write f32 kv
// and (cols<128) the tiled bf16 K buffer (formula verified passing r12-r21).
// blocks 0..511 -> branch1 (KS=8, KTp=4); 512..2559 -> branch2 (KS=4, KTp=16).
// ---------------------------------------------------------------------------
__global__ void reduce_kv_fused_kernel(
    const float* __restrict__ p1, float* __restrict__ kv1, unsigned short* __restrict__ kb1,
    const float* __restrict__ p2, float* __restrict__ kv2, unsigned short* __restrict__ kb2) {
    int bx = blockIdx.x;
    int br1 = (bx < 512);
    int m = br1 ? bx : bx - 512;
    const float* part = br1 ? p1 : p2;
    float* kv = br1 ? kv1 : kv2;
    unsigned short* kb = br1 ? kb1 : kb2;
    int MN = br1 ? 512 * 256 : 2048 * 256;
    int KS = br1 ? 8 : 4;
    int KTp = br1 ? 4 : 16;

    int c = threadIdx.x;
    float v = 0.f;
    for (int z = 0; z < KS; ++z) v += part[(long)z * MN + m * C_DIM + c];
    kv[m * C_DIM + c] = v;
    if (c < 128) {
        int h = c >> 5, cc = c & 31, kt = m >> 7, mi = m & 127;
        kb[((long)(h * KTp + kt) * 128 + mi) * 32 + cc] = f2bf(v);
    }
}

// ---------------------------------------------------------------------------
// im2col for SR conv.
// ---------------------------------------------------------------------------
template <int S>
__global__ void im2col_kernel(const float* __restrict__ x, float* __restrict__ im, int Ws) {
    constexpr int T = S * S;
    __shared__ float patch[T * 257];
    int m = blockIdx.x;
    int z = m % ZZ;
    int wo = (m / ZZ) % Ws;
    int ho = m / (ZZ * Ws);
    int t = threadIdx.x;
#pragma unroll
    for (int tap = 0; tap < T; ++tap) {
        int kh = tap / S, kw = tap % S;
        int row = (ho * S + kh) * (WW * ZZ) + (wo * S + kw) * ZZ + z;
        patch[tap * 257 + t] = x[row * C_DIM + t];
    }
    __syncthreads();
#pragma unroll
    for (int rep = 0; rep < T; ++rep) {
        int k = rep * 256 + t;
        int ci = k / T, tap = k % T;
        im[(long)m * (256 * T) + k] = patch[tap * 257 + ci];
    }
}

// ---------------------------------------------------------------------------
// Fused depthwise 3x3x1 conv on V + residual for BOTH branches.
// Writes tiled V^T bf16 with the swapped-QK slot permutation.
// ---------------------------------------------------------------------------
__global__ void dw_conv_fused_kernel(const float* __restrict__ kv1, const float* __restrict__ lw1,
                                     const float* __restrict__ lb1, unsigned short* __restrict__ vt1,
                                     const float* __restrict__ kv2, const float* __restrict__ lw2,
                                     const float* __restrict__ lb2, unsigned short* __restrict__ vt2) {
    int bx = blockIdx.x;
    int b1 = (bx < 512);
    int m = b1 ? bx : bx - 512;
    const float* kv = b1 ? kv1 : kv2;
    const float* lw = b1 ? lw1 : lw2;
    const float* lb = b1 ? lb1 : lb2;
    unsigned short* vt = b1 ? vt1 : vt2;
    int Ws = b1 ? 8 : 16, Hs = b1 ? 8 : 16, KT = b1 ? 4 : 16;

    int ch = threadIdx.x;
    int z = m % ZZ;
    int wo = (m / ZZ) % Ws;
    int ho = m / (ZZ * Ws);
    float acc = lb[ch];
#pragma unroll
    for (int kh = 0; kh < 3; ++kh) {
        int h = ho + kh - 1;
        if (h < 0 || h >= Hs) continue;
#pragma unroll
        for (int kw = 0; kw < 3; ++kw) {
            int w2 = wo + kw - 1;
            if (w2 < 0 || w2 >= Ws) continue;
            int mm = (h * Ws + w2) * ZZ + z;
            acc += kv[mm * C_DIM + 128 + ch] * lw[ch * 9 + kh * 3 + kw];
        }
    }
    int hh = ch >> 5, d = ch & 31, kt = m >> 7, mi = m & 127;
    int a = mi >> 5, u = (mi >> 4) & 1, g = (mi >> 2) & 3, v = mi & 3;
    int s = (a << 5) | (g << 3) | (u << 2) | v;
    vt[((long)(hh * KT + kt) * 32 + d) * 128 + s] = f2bf(kv[m * C_DIM + 128 + ch] + acc);
}

// ---------------------------------------------------------------------------
// Fused MFMA flash attention (passing r18-r21 structure), output now BF16
// (catb), feeding the ABF16 proj GEMM directly.
// ---------------------------------------------------------------------------
__global__ __launch_bounds__(256, 2) void attn_fused_kernel(
    const unsigned short* __restrict__ qb,
    const unsigned short* __restrict__ kb1, const unsigned short* __restrict__ vt1,
    const unsigned short* __restrict__ kb2, const unsigned short* __restrict__ vt2,
    unsigned short* __restrict__ catb) {
    int wave = threadIdx.x >> 6;
    int lane = threadIdx.x & 63;
    int lg = lane >> 4;
    int lc = lane & 15;
    int by = blockIdx.y;
    int big = ((by >> 2) == 0);  // by 0..3 = branch-2 (M=2048), dispatched first
    int head = by & 3;
    const unsigned short* kb = big ? kb2 : kb1;
    const unsigned short* vt = big ? vt2 : vt1;
    int KT = big ? 16 : 4;
    int col_base = big ? 128 : 0;
    int q0 = blockIdx.x * 128 + wave * 32;

    bf16x8 qf0 = *reinterpret_cast<const bf16x8*>(qb + (long)(q0 + lc) * C_DIM + col_base + head * HD + lg * 8);
    bf16x8 qf1 = *reinterpret_cast<const bf16x8*>(qb + (long)(q0 + 16 + lc) * C_DIM + col_base + head * HD + lg * 8);

    const unsigned short* kbase = kb + (long)head * KT * 4096;
    const unsigned short* vbase = vt + (long)head * KT * 4096;

    f32x4 o00 = {0.f, 0.f, 0.f, 0.f}, o01 = {0.f, 0.f, 0.f, 0.f};
    f32x4 o10 = {0.f, 0.f, 0.f, 0.f}, o11 = {0.f, 0.f, 0.f, 0.f};
    float lsum0 = 0.f, lsum1 = 0.f;

    bf16x8 kf[8];
    bf16x8 vf0c[4], vf1c[4];
#pragma unroll
    for (int c = 0; c < 8; ++c)
        kf[c] = *reinterpret_cast<const bf16x8*>(kbase + (16 * c + lc) * 32 + lg * 8);
#pragma unroll
    for (int c2 = 0; c2 < 4; ++c2) {
        vf0c[c2] = *reinterpret_cast<const bf16x8*>(vbase + lc * 128 + c2 * 32 + lg * 8);
        vf1c[c2] = *reinterpret_cast<const bf16x8*>(vbase + (16 + lc) * 128 + c2 * 32 + lg * 8);
    }

    for (int kt = 0; kt < KT; ++kt) {
        f32x4 s0[8], s1[8];
        f32x4 z = {0.f, 0.f, 0.f, 0.f};
#pragma unroll
        for (int c = 0; c < 8; ++c) {
            s0[c] = __builtin_amdgcn_mfma_f32_16x16x32_bf16(kf[c], qf0, z, 0, 0, 0);
            s1[c] = __builtin_amdgcn_mfma_f32_16x16x32_bf16(kf[c], qf1, z, 0, 0, 0);
        }
        bf16x8 vf0n[4], vf1n[4];
        if (kt + 1 < KT) {
            const unsigned short* knext = kbase + (long)(kt + 1) * 4096;
            const unsigned short* vnext = vbase + (long)(kt + 1) * 4096;
#pragma unroll
            for (int c = 0; c < 8; ++c)
                kf[c] = *reinterpret_cast<const bf16x8*>(knext + (16 * c + lc) * 32 + lg * 8);
#pragma unroll
            for (int c2 = 0; c2 < 4; ++c2) {
                vf0n[c2] = *reinterpret_cast<const bf16x8*>(vnext + lc * 128 + c2 * 32 + lg * 8);
                vf1n[c2] = *reinterpret_cast<const bf16x8*>(vnext + (16 + lc) * 128 + c2 * 32 + lg * 8);
            }
        }
#pragma unroll
        for (int c2 = 0; c2 < 4; ++c2) {
            unsigned int w0, w1, w2, w3;
            {
                int c = 2 * c2;
                float p0 = __builtin_amdgcn_exp2f(s0[c][0]);
                float p1 = __builtin_amdgcn_exp2f(s0[c][1]);
                float p2 = __builtin_amdgcn_exp2f(s0[c][2]);
                float p3 = __builtin_amdgcn_exp2f(s0[c][3]);
                lsum0 += (p0 + p1) + (p2 + p3);
                w0 = cvtpk_bf16(p0, p1);
                w1 = cvtpk_bf16(p2, p3);
            }
            {
                int c = 2 * c2 + 1;
                float p0 = __builtin_amdgcn_exp2f(s0[c][0]);
                float p1 = __builtin_amdgcn_exp2f(s0[c][1]);
                float p2 = __builtin_amdgcn_exp2f(s0[c][2]);
                float p3 = __builtin_amdgcn_exp2f(s0[c][3]);
                lsum0 += (p0 + p1) + (p2 + p3);
                w2 = cvtpk_bf16(p0, p1);
                w3 = cvtpk_bf16(p2, p3);
            }
            u32x4 pw = {w0, w1, w2, w3};
            bf16x8 pa = __builtin_bit_cast(bf16x8, pw);
            o00 = __builtin_amdgcn_mfma_f32_16x16x32_bf16(pa, vf0c[c2], o00, 0, 0, 0);
            o01 = __builtin_amdgcn_mfma_f32_16x16x32_bf16(pa, vf1c[c2], o01, 0, 0, 0);
        }
#pragma unroll
        for (int c2 = 0; c2 < 4; ++c2) {
            unsigned int w0, w1, w2, w3;
            {
                int c = 2 * c2;
                float p0 = __builtin_amdgcn_exp2f(s1[c][0]);
                float p1 = __builtin_amdgcn_exp2f(s1[c][1]);
                float p2 = __builtin_amdgcn_exp2f(s1[c][2]);
                float p3 = __builtin_amdgcn_exp2f(s1[c][3]);
                lsum1 += (p0 + p1) + (p2 + p3);
                w0 = cvtpk_bf16(p0, p1);
                w1 = cvtpk_bf16(p2, p3);
            }
            {
                int c = 2 * c2 + 1;
                float p0 = __builtin_amdgcn_exp2f(s1[c][0]);
                float p1 = __builtin_amdgcn_exp2f(s1[c][1]);
                float p2 = __builtin_amdgcn_exp2f(s1[c][2]);
                float p3 = __builtin_amdgcn_exp2f(s1[c][3]);
                lsum1 += (p0 + p1) + (p2 + p3);
                w2 = cvtpk_bf16(p0, p1);
                w3 = cvtpk_bf16(p2, p3);
            }
            u32x4 pw = {w0, w1, w2, w3};
            bf16x8 pa = __builtin_bit_cast(bf16x8, pw);
            o10 = __builtin_amdgcn_mfma_f32_16x16x32_bf16(pa, vf0c[c2], o10, 0, 0, 0);
            o11 = __builtin_amdgcn_mfma_f32_16x16x32_bf16(pa, vf1c[c2], o11, 0, 0, 0);
        }
        if (kt + 1 < KT) {
#pragma unroll
            for (int c2 = 0; c2 < 4; ++c2) {
                vf0c[c2] = vf0n[c2];
                vf1c[c2] = vf1n[c2];
            }
        }
    }
    lsum0 += __shfl_xor(lsum0, 16);
    lsum0 += __shfl_xor(lsum0, 32);
    lsum1 += __shfl_xor(lsum1, 16);
    lsum1 += __shfl_xor(lsum1, 32);
#pragma unroll
    for (int r = 0; r < 4; ++r) {
        float ls = __shfl(lsum0, lg * 4 + r);
        float inv = 1.f / ls;
        int row = q0 + lg * 4 + r;
        catb[(long)row * C_DIM + col_base + head * HD + lc] = f2bf(o00[r] * inv);
        catb[(long)row * C_DIM + col_base + head * HD + 16 + lc] = f2bf(o01[r] * inv);
    }
#pragma unroll
    for (int r = 0; r < 4; ++r) {
        float ls = __shfl(lsum1, lg * 4 + r);
        float inv = 1.f / ls;
        int row = q0 + 16 + lg * 4 + r;
        catb[(long)row * C_DIM + col_base + head * HD + lc] = f2bf(o10[r] * inv);
        catb[(long)row * C_DIM + col_base + head * HD + 16 + lc] = f2bf(o11[r] * inv);
    }
}

// ---------------------------------------------------------------------------
extern "C" void kernel_launch(void* const* d_in, const int* in_sizes, int n_in,
                              void* d_out, int out_size, void* d_ws, size_t ws_size,
                              hipStream_t stream) {
    const float* x      = (const float*)d_in[0];
    const float* Wq     = (const float*)d_in[1];
    const float* sr1_w  = (const float*)d_in[2];
    const float* sr1_b  = (const float*)d_in[3];
    const float* ln1_w  = (const float*)d_in[4];
    const float* ln1_b  = (const float*)d_in[5];
    const float* sr2_w  = (const float*)d_in[6];
    const float* sr2_b  = (const float*)d_in[7];
    const float* ln2_w  = (const float*)d_in[8];
    const float* ln2_b  = (const float*)d_in[9];
    const float* Wkv1   = (const float*)d_in[10];
    const float* Wkv2   = (const float*)d_in[11];
    const float* lc1_w  = (const float*)d_in[12];
    const float* lc1_b  = (const float*)d_in[13];
    const float* lc2_w  = (const float*)d_in[14];
    const float* lc2_b  = (const float*)d_in[15];
    const float* proj_w = (const float*)d_in[16];
    const float* proj_b = (const float*)d_in[17];
    float* out = (float*)d_out;
    char* wsb = (char*)d_ws;

    // Workspace (needs ~35.9 MB; proven available since r4-r19 ran KS2=4
    // which gated on ws_size >= 35.9 MB — r20's unconditional switch was
    // timing-neutral, so that branch had been taken).
    // buf0: part1 (16x0.5MB) -> kv1 partials (8x0.5MB=4MB)
    // im:   im1 -> im2 -> kv2 partials (4x2MB=8MB)
    // hi (27.5MB..35.9MB): part2 (4x2MB) -> catb (bf16 cat, 4MB)
    float* buf0 = (float*)wsb;                                  // 8 MB
    unsigned short* qb = (unsigned short*)(wsb + 8388608);      // 4 MB
    float* im = (float*)(wsb + 12582912);                       // 8 MB
    float* xr1 = (float*)(wsb + 20971520);
    float* kv1 = (float*)(wsb + 21495808);
    unsigned short* kb1 = (unsigned short*)(wsb + 22020096);
    unsigned short* vt1 = (unsigned short*)(wsb + 22151168);
    float* xr2 = (float*)(wsb + 22282240);
    float* kv2 = (float*)(wsb + 24379392);
    unsigned short* kb2 = (unsigned short*)(wsb + 26476544);
    unsigned short* vt2 = (unsigned short*)(wsb + 27000832);
    float* hi = (float*)(wsb + 27525120);                       // 8.4 MB region

    float* part1 = buf0;
    float* part2 = hi;
    float* kv1part = buf0;
    float* kv2part = im;
    unsigned short* catb = (unsigned short*)hi;

    // 1. q = bf16(scale * x @ Wq.T)
    gemm_split_kernel<false><<<dim3(4, 128, 1), 256, 0, stream>>>(x, Wq, nullptr, (float*)qb, 8192, 256, 256, qb);

    // 2-5. SR convs (im2col + split-K GEMM), both branches
    im2col_kernel<4><<<512, 256, 0, stream>>>(x, im, 8);
    gemm_split_kernel<false><<<dim3(4, 8, 16), 256, 0, stream>>>(im, sr1_w, nullptr, part1, 512, 256, 4096, nullptr);
    im2col_kernel<2><<<2048, 256, 0, stream>>>(x, im, 16);
    gemm_split_kernel<false><<<dim3(4, 32, 4), 256, 0, stream>>>(im, sr2_w, nullptr, part2, 2048, 256, 1024, nullptr);

    // 6. fused reduce + LN + GELU (both branches)
    reduce_ln_gelu_fused_kernel<<<2560, 256, 0, stream>>>(part1, sr1_b, ln1_w, ln1_b, xr1,
                                                          part2, sr2_b, ln2_w, ln2_b, xr2);

    // 7-8. kv GEMMs (split-K), partials into buf0 / im (both now dead)
    gemm_split_kernel<false><<<dim3(4, 8, 8), 256, 0, stream>>>(xr1, Wkv1, nullptr, kv1part, 512, 256, 256, nullptr);
    gemm_split_kernel<false><<<dim3(4, 32, 4), 256, 0, stream>>>(xr2, Wkv2, nullptr, kv2part, 2048, 256, 256, nullptr);

    // 9. fused kv reduce (writes f32 kv + tiled bf16 K)
    reduce_kv_fused_kernel<<<2560, 256, 0, stream>>>(kv1part, kv1, kb1, kv2part, kv2, kb2);

    // 10. fused depthwise conv (both branches)
    dw_conv_fused_kernel<<<2560, 128, 0, stream>>>(kv1, lc1_w, lc1_b, vt1, kv2, lc2_w, lc2_b, vt2);

    // 11. fused attention -> bf16 cat
    attn_fused_kernel<<<dim3(64, 8), 256, 0, stream>>>(qb, kb1, vt1, kb2, vt2, catb);

    // 12. out = cat @ proj_w.T + proj_b (bf16-A GEMM)
    gemm_split_kernel<true><<<dim3(4, 128, 1), 256, 0, stream>>>(catb, proj_w, proj_b, out, 8192, 256, 256, nullptr);
}

// Round 23
// 99.761 us; speedup vs baseline: 1.2311x; 1.1925x over previous
//
#include <hip/hip_runtime.h>
#include <math.h>

#define C_DIM 256
#define HH 32
#define WW 32
#define ZZ 8
#define HD 32

typedef __attribute__((ext_vector_type(8))) short bf16x8;
typedef __attribute__((ext_vector_type(4))) float f32x4;
typedef __attribute__((ext_vector_type(4))) unsigned int u32x4;

__device__ inline unsigned short f2bf(float f) {
    unsigned int u = __builtin_bit_cast(unsigned int, f);
    u += 0x7FFF + ((u >> 16) & 1);
    return (unsigned short)(u >> 16);
}
__device__ inline unsigned int cvtpk_bf16(float a, float b) {
    unsigned int r;
    asm("v_cvt_pk_bf16_f32 %0, %1, %2" : "=v"(r) : "v"(a), "v"(b));
    return r;  // lo = bf16(a), hi = bf16(b)
}

// softmax scale with log2(e) folded in: exp2(q*k*QSCALE) == exp(q*k/sqrt(32))
#define QSCALE (0.17677669529663689f * 1.4426950408889634f)

// ---------------------------------------------------------------------------
// GEMM tile job (device fn): C[i,j] = sum_k A[i,k]*B[j,k] over K-chunk z of
// KS; split-bf16 via v_cvt_pk (exact residual), double-buffered LDS.
// qb_out != null: write f2bf(val*QSCALE) instead of C (Wq job).
// Body is the verified r19-r22 GEMM inner loop, only index plumbing changed.
// ---------------------------------------------------------------------------
__device__ __forceinline__ void gemm_job(
    const float* __restrict__ A, const float* __restrict__ B,
    const float* __restrict__ bias, float* __restrict__ C,
    int M, int N, int K, int KS, int z, int bx, int by,
    unsigned short* __restrict__ qb_out,
    unsigned short (*Ah)[2560], unsigned short (*Al)[2560],
    unsigned short (*Bh)[2560], unsigned short (*Bl)[2560]) {
    int t = threadIdx.x;
    int wave = t >> 6, lane = t & 63;
    int lg = lane >> 4, lc = lane & 15;
    int wm = wave >> 1, wn = wave & 1;
    int m0 = by * 64, n0 = bx * 64;
    int Kc = K / KS;
    int kbeg = z * Kc;
    float* Cz = C + (long)z * M * N;
    int srow = t >> 2, sc8 = (t & 3) * 8;
    const float* aBase = A + (long)(m0 + srow) * K + kbeg + sc8;
    const float* bBase = B + (long)(n0 + srow) * K + kbeg + sc8;
    int nIter = Kc / 32;

    f32x4 acc[2][2];
#pragma unroll
    for (int i = 0; i < 2; ++i)
#pragma unroll
        for (int j = 0; j < 2; ++j) acc[i][j] = (f32x4){0.f, 0.f, 0.f, 0.f};

    auto split8 = [](f32x4 v0, f32x4 v1, u32x4& hw, u32x4& lw) {
        float av[8] = {v0[0], v0[1], v0[2], v0[3], v1[0], v1[1], v1[2], v1[3]};
#pragma unroll
        for (int p = 0; p < 4; ++p) {
            float x0 = av[2 * p], x1 = av[2 * p + 1];
            unsigned int w = cvtpk_bf16(x0, x1);
            float h0 = __builtin_bit_cast(float, w << 16);
            float h1 = __builtin_bit_cast(float, w & 0xFFFF0000u);
            hw[p] = w;
            lw[p] = cvtpk_bf16(x0 - h0, x1 - h1);
        }
    };
    auto stage = [&](int buf, int k) {
        f32x4 a0 = *reinterpret_cast<const f32x4*>(aBase + k * 32);
        f32x4 a1 = *reinterpret_cast<const f32x4*>(aBase + k * 32 + 4);
        u32x4 hw, lw;
        split8(a0, a1, hw, lw);
        *reinterpret_cast<u32x4*>(&Ah[buf][srow * 40 + sc8]) = hw;
        *reinterpret_cast<u32x4*>(&Al[buf][srow * 40 + sc8]) = lw;
        f32x4 b0 = *reinterpret_cast<const f32x4*>(bBase + k * 32);
        f32x4 b1 = *reinterpret_cast<const f32x4*>(bBase + k * 32 + 4);
        split8(b0, b1, hw, lw);
        *reinterpret_cast<u32x4*>(&Bh[buf][srow * 40 + sc8]) = hw;
        *reinterpret_cast<u32x4*>(&Bl[buf][srow * 40 + sc8]) = lw;
    };

    stage(0, 0);
    __syncthreads();

    for (int k = 0; k < nIter; ++k) {
        int cur = k & 1;
        bool more = (k + 1 < nIter);
        bf16x8 afh[2], afl[2], bfh[2], bfl[2];
#pragma unroll
        for (int i = 0; i < 2; ++i) {
            int ar = wm * 32 + i * 16 + lc;
            afh[i] = *reinterpret_cast<const bf16x8*>(&Ah[cur][ar * 40 + lg * 8]);
            afl[i] = *reinterpret_cast<const bf16x8*>(&Al[cur][ar * 40 + lg * 8]);
            int br = wn * 32 + i * 16 + lc;
            bfh[i] = *reinterpret_cast<const bf16x8*>(&Bh[cur][br * 40 + lg * 8]);
            bfl[i] = *reinterpret_cast<const bf16x8*>(&Bl[cur][br * 40 + lg * 8]);
        }
#pragma unroll
        for (int i = 0; i < 2; ++i)
#pragma unroll
            for (int j = 0; j < 2; ++j) {
                acc[i][j] = __builtin_amdgcn_mfma_f32_16x16x32_bf16(afh[i], bfh[j], acc[i][j], 0, 0, 0);
                acc[i][j] = __builtin_amdgcn_mfma_f32_16x16x32_bf16(afh[i], bfl[j], acc[i][j], 0, 0, 0);
                acc[i][j] = __builtin_amdgcn_mfma_f32_16x16x32_bf16(afl[i], bfh[j], acc[i][j], 0, 0, 0);
            }
        if (more) {
            stage(cur ^ 1, k + 1);
            __syncthreads();
        }
    }
#pragma unroll
    for (int i = 0; i < 2; ++i)
#pragma unroll
        for (int j = 0; j < 2; ++j)
#pragma unroll
            for (int r = 0; r < 4; ++r) {
                int row = m0 + wm * 32 + i * 16 + lg * 4 + r;
                int col = n0 + wn * 32 + j * 16 + lc;
                float bv = bias ? bias[col] : 0.f;
                float val = acc[i][j][r] + bv;
                if (qb_out) {
                    qb_out[(long)row * N + col] = f2bf(val * QSCALE);
                } else {
                    Cz[(long)row * N + col] = val;
                }
            }
}

// ---------------------------------------------------------------------------
// Fused Wq + sr1 + sr2 GEMMs. Grid 1024 blocks:
//   0..511   : Wq   (M=8192, K=256,  KS=1)  -> qb epilogue
//   512..767 : sr1  (M=512,  K=4096, KS=8)  -> part1
//   768..1023: sr2  (M=2048, K=1024, KS=2)  -> part2
// ---------------------------------------------------------------------------
__global__ __launch_bounds__(256) void qsr_fused_kernel(
    const float* __restrict__ x, const float* __restrict__ Wq,
    unsigned short* __restrict__ qb,
    const float* __restrict__ im1, const float* __restrict__ sr1_w, float* __restrict__ part1,
    const float* __restrict__ im2, const float* __restrict__ sr2_w, float* __restrict__ part2) {
    __shared__ unsigned short Ah[2][2560], Al[2][2560], Bh[2][2560], Bl[2][2560];
    int b = blockIdx.x;
    if (b < 512) {
        gemm_job(x, Wq, nullptr, nullptr, 8192, 256, 256, 1, 0, b & 3, b >> 2, qb, Ah, Al, Bh, Bl);
    } else if (b < 768) {
        int l = b - 512;
        gemm_job(im1, sr1_w, nullptr, part1, 512, 256, 4096, 8, l >> 5, l & 3, (l >> 2) & 7, nullptr, Ah, Al, Bh, Bl);
    } else {
        int l = b - 768;
        gemm_job(im2, sr2_w, nullptr, part2, 2048, 256, 1024, 2, l >> 7, l & 3, (l >> 2) & 31, nullptr, Ah, Al, Bh, Bl);
    }
}

// ---------------------------------------------------------------------------
// Fused kv1 + kv2 GEMMs. Grid 768 blocks:
//   0..255  : kv1 (M=512,  K=256, KS=8) -> kv1part
//   256..767: kv2 (M=2048, K=256, KS=4) -> kv2part
// ---------------------------------------------------------------------------
__global__ __launch_bounds__(256) void kv_fused_gemm_kernel(
    const float* __restrict__ xr1, const float* __restrict__ Wkv1, float* __restrict__ kv1part,
    const float* __restrict__ xr2, const float* __restrict__ Wkv2, float* __restrict__ kv2part) {
    __shared__ unsigned short Ah[2][2560], Al[2][2560], Bh[2][2560], Bl[2][2560];
    int b = blockIdx.x;
    if (b < 256) {
        gemm_job(xr1, Wkv1, nullptr, kv1part, 512, 256, 256, 8, b >> 5, b & 3, (b >> 2) & 7, nullptr, Ah, Al, Bh, Bl);
    } else {
        int l = b - 256;
        gemm_job(xr2, Wkv2, nullptr, kv2part, 2048, 256, 256, 4, l >> 7, l & 3, (l >> 2) & 31, nullptr, Ah, Al, Bh, Bl);
    }
}

// ---------------------------------------------------------------------------
// proj GEMM: A is bf16 (exact), 2 MFMAs per (i,j).
// ---------------------------------------------------------------------------
__global__ __launch_bounds__(256) void gemm_projb_kernel(
    const unsigned short* __restrict__ A, const float* __restrict__ B,
    const float* __restrict__ bias, float* __restrict__ C, int M, int N, int K) {
    __shared__ unsigned short Ah[2][2560], Bh[2][2560], Bl[2][2560];
    int t = threadIdx.x;
    int wave = t >> 6, lane = t & 63;
    int lg = lane >> 4, lc = lane & 15;
    int wm = wave >> 1, wn = wave & 1;
    int m0 = blockIdx.y * 64, n0 = blockIdx.x * 64;
    int srow = t >> 2, sc8 = (t & 3) * 8;
    const unsigned short* aBase = A + (long)(m0 + srow) * K + sc8;
    const float* bBase = B + (long)(n0 + srow) * K + sc8;
    int nIter = K / 32;

    f32x4 acc[2][2];
#pragma unroll
    for (int i = 0; i < 2; ++i)
#pragma unroll
        for (int j = 0; j < 2; ++j) acc[i][j] = (f32x4){0.f, 0.f, 0.f, 0.f};

    auto split8 = [](f32x4 v0, f32x4 v1, u32x4& hw, u32x4& lw) {
        float av[8] = {v0[0], v0[1], v0[2], v0[3], v1[0], v1[1], v1[2], v1[3]};
#pragma unroll
        for (int p = 0; p < 4; ++p) {
            float x0 = av[2 * p], x1 = av[2 * p + 1];
            unsigned int w = cvtpk_bf16(x0, x1);
            float h0 = __builtin_bit_cast(float, w << 16);
            float h1 = __builtin_bit_cast(float, w & 0xFFFF0000u);
            hw[p] = w;
            lw[p] = cvtpk_bf16(x0 - h0, x1 - h1);
        }
    };
    auto stage = [&](int buf, int k) {
        u32x4 aw = *reinterpret_cast<const u32x4*>(aBase + k * 32);
        *reinterpret_cast<u32x4*>(&Ah[buf][srow * 40 + sc8]) = aw;
        f32x4 b0 = *reinterpret_cast<const f32x4*>(bBase + k * 32);
        f32x4 b1 = *reinterpret_cast<const f32x4*>(bBase + k * 32 + 4);
        u32x4 hw, lw;
        split8(b0, b1, hw, lw);
        *reinterpret_cast<u32x4*>(&Bh[buf][srow * 40 + sc8]) = hw;
        *reinterpret_cast<u32x4*>(&Bl[buf][srow * 40 + sc8]) = lw;
    };

    stage(0, 0);
    __syncthreads();

    for (int k = 0; k < nIter; ++k) {
        int cur = k & 1;
        bool more = (k + 1 < nIter);
        bf16x8 af[2], bfh[2], bfl[2];
#pragma unroll
        for (int i = 0; i < 2; ++i) {
            int ar = wm * 32 + i * 16 + lc;
            af[i] = *reinterpret_cast<const bf16x8*>(&Ah[cur][ar * 40 + lg * 8]);
            int br = wn * 32 + i * 16 + lc;
            bfh[i] = *reinterpret_cast<const bf16x8*>(&Bh[cur][br * 40 + lg * 8]);
            bfl[i] = *reinterpret_cast<const bf16x8*>(&Bl[cur][br * 40 + lg * 8]);
        }
#pragma unroll
        for (int i = 0; i < 2; ++i)
#pragma unroll
            for (int j = 0; j < 2; ++j) {
                acc[i][j] = __builtin_amdgcn_mfma_f32_16x16x32_bf16(af[i], bfh[j], acc[i][j], 0, 0, 0);
                acc[i][j] = __builtin_amdgcn_mfma_f32_16x16x32_bf16(af[i], bfl[j], acc[i][j], 0, 0, 0);
            }
        if (more) {
            stage(cur ^ 1, k + 1);
            __syncthreads();
        }
    }
#pragma unroll
    for (int i = 0; i < 2; ++i)
#pragma unroll
        for (int j = 0; j < 2; ++j)
#pragma unroll
            for (int r = 0; r < 4; ++r) {
                int row = m0 + wm * 32 + i * 16 + lg * 4 + r;
                int col = n0 + wn * 32 + j * 16 + lc;
                C[(long)row * N + col] = acc[i][j][r] + bias[col];
            }
}

// ---------------------------------------------------------------------------
// Fused (both branches): sum split-K planes + bias, LayerNorm + exact GELU.
// blocks 0..511 -> branch1 (KS=8); 512..2559 -> branch2 (KS=2).
// ---------------------------------------------------------------------------
__global__ void reduce_ln_gelu_fused_kernel(
    const float* __restrict__ p1, const float* __restrict__ b1f,
    const float* __restrict__ g1, const float* __restrict__ bb1, float* __restrict__ x1,
    const float* __restrict__ p2, const float* __restrict__ b2f,
    const float* __restrict__ g2, const float* __restrict__ bb2, float* __restrict__ x2) {
    int bx = blockIdx.x;
    int br1 = (bx < 512);
    int m = br1 ? bx : bx - 512;
    const float* part = br1 ? p1 : p2;
    const float* bias = br1 ? b1f : b2f;
    const float* g = br1 ? g1 : g2;
    const float* bb = br1 ? bb1 : bb2;
    float* xr = br1 ? x1 : x2;
    int MN = br1 ? 512 * 256 : 2048 * 256;
    int KS = br1 ? 8 : 2;

    int c = threadIdx.x;
    float v = bias[c];
    for (int z = 0; z < KS; ++z) v += part[(long)z * MN + m * C_DIM + c];
    __shared__ float wred[4];
    float s = v;
    for (int off = 32; off; off >>= 1) s += __shfl_down(s, off);
    if ((c & 63) == 0) wred[c >> 6] = s;
    __syncthreads();
    float mean = (wred[0] + wred[1] + wred[2] + wred[3]) * (1.f / 256.f);
    __syncthreads();
    float d = v - mean;
    float s2 = d * d;
    for (int off = 32; off; off >>= 1) s2 += __shfl_down(s2, off);
    if ((c & 63) == 0) wred[c >> 6] = s2;
    __syncthreads();
    float var = (wred[0] + wred[1] + wred[2] + wred[3]) * (1.f / 256.f);
    float y = d * rsqrtf(var + 1e-5f) * g[c] + bb[c];
    float ge = 0.5f * y * (1.f + erff(y * 0.70710678118654752f));
    xr[m * C_DIM + c] = ge;
}

// ---------------------------------------------------------------------------
// Fused kv reduce (both branches): f32 kv + tiled bf16 K.
// ---------------------------------------------------------------------------
__global__ void reduce_kv_fused_kernel(
    const float* __restrict__ p1, float* __restrict__ kv1, unsigned short* __restrict__ kb1,
    const float* __restrict__ p2, float* __restrict__ kv2, unsigned short* __restrict__ kb2) {
    int bx = blockIdx.x;
    int br1 = (bx < 512);
    int m = br1 ? bx : bx - 512;
    const float* part = br1 ? p1 : p2;
    float* kv = br1 ? kv1 : kv2;
    unsigned short* kb = br1 ? kb1 : kb2;
    int MN = br1 ? 512 * 256 : 2048 * 256;
    int KS = br1 ? 8 : 4;
    int KTp = br1 ? 4 : 16;

    int c = threadIdx.x;
    float v = 0.f;
    for (int z = 0; z < KS; ++z) v += part[(long)z * MN + m * C_DIM + c];
    kv[m * C_DIM + c] = v;
    if (c < 128) {
        int h = c >> 5, cc = c & 31, kt = m >> 7, mi = m & 127;
        kb[((long)(h * KTp + kt) * 128 + mi) * 32 + cc] = f2bf(v);
    }
}

// ---------------------------------------------------------------------------
// im2col for SR conv.
// ---------------------------------------------------------------------------
template <int S>
__global__ void im2col_kernel(const float* __restrict__ x, float* __restrict__ im, int Ws) {
    constexpr int T = S * S;
    __shared__ float patch[T * 257];
    int m = blockIdx.x;
    int z = m % ZZ;
    int wo = (m / ZZ) % Ws;
    int ho = m / (ZZ * Ws);
    int t = threadIdx.x;
#pragma unroll
    for (int tap = 0; tap < T; ++tap) {
        int kh = tap / S, kw = tap % S;
        int row = (ho * S + kh) * (WW * ZZ) + (wo * S + kw) * ZZ + z;
        patch[tap * 257 + t] = x[row * C_DIM + t];
    }
    __syncthreads();
#pragma unroll
    for (int rep = 0; rep < T; ++rep) {
        int k = rep * 256 + t;
        int ci = k / T, tap = k % T;
        im[(long)m * (256 * T) + k] = patch[tap * 257 + ci];
    }
}

// ---------------------------------------------------------------------------
// Fused depthwise 3x3x1 conv on V + residual for BOTH branches (tiled V^T
// bf16 with the swapped-QK slot permutation).
// ---------------------------------------------------------------------------
__global__ void dw_conv_fused_kernel(const float* __restrict__ kv1, const float* __restrict__ lw1,
                                     const float* __restrict__ lb1, unsigned short* __restrict__ vt1,
                                     const float* __restrict__ kv2, const float* __restrict__ lw2,
                                     const float* __restrict__ lb2, unsigned short* __restrict__ vt2) {
    int bx = blockIdx.x;
    int b1 = (bx < 512);
    int m = b1 ? bx : bx - 512;
    const float* kv = b1 ? kv1 : kv2;
    const float* lw = b1 ? lw1 : lw2;
    const float* lb = b1 ? lb1 : lb2;
    unsigned short* vt = b1 ? vt1 : vt2;
    int Ws = b1 ? 8 : 16, Hs = b1 ? 8 : 16, KT = b1 ? 4 : 16;

    int ch = threadIdx.x;
    int z = m % ZZ;
    int wo = (m / ZZ) % Ws;
    int ho = m / (ZZ * Ws);
    float acc = lb[ch];
#pragma unroll
    for (int kh = 0; kh < 3; ++kh) {
        int h = ho + kh - 1;
        if (h < 0 || h >= Hs) continue;
#pragma unroll
        for (int kw = 0; kw < 3; ++kw) {
            int w2 = wo + kw - 1;
            if (w2 < 0 || w2 >= Ws) continue;
            int mm = (h * Ws + w2) * ZZ + z;
            acc += kv[mm * C_DIM + 128 + ch] * lw[ch * 9 + kh * 3 + kw];
        }
    }
    int hh = ch >> 5, d = ch & 31, kt = m >> 7, mi = m & 127;
    int a = mi >> 5, u = (mi >> 4) & 1, g = (mi >> 2) & 3, v = mi & 3;
    int s = (a << 5) | (g << 3) | (u << 2) | v;
    vt[((long)(hh * KT + kt) * 32 + d) * 128 + s] = f2bf(kv[m * C_DIM + 128 + ch] + acc);
}

// ---------------------------------------------------------------------------
// Fused MFMA flash attention (passing r18-r22 structure), bf16 output.
// ---------------------------------------------------------------------------
__global__ __launch_bounds__(256, 2) void attn_fused_kernel(
    const unsigned short* __restrict__ qb,
    const unsigned short* __restrict__ kb1, const unsigned short* __restrict__ vt1,
    const unsigned short* __restrict__ kb2, const unsigned short* __restrict__ vt2,
    unsigned short* __restrict__ catb) {
    int wave = threadIdx.x >> 6;
    int lane = threadIdx.x & 63;
    int lg = lane >> 4;
    int lc = lane & 15;
    int by = blockIdx.y;
    int big = ((by >> 2) == 0);
    int head = by & 3;
    const unsigned short* kb = big ? kb2 : kb1;
    const unsigned short* vt = big ? vt2 : vt1;
    int KT = big ? 16 : 4;
    int col_base = big ? 128 : 0;
    int q0 = blockIdx.x * 128 + wave * 32;

    bf16x8 qf0 = *reinterpret_cast<const bf16x8*>(qb + (long)(q0 + lc) * C_DIM + col_base + head * HD + lg * 8);
    bf16x8 qf1 = *reinterpret_cast<const bf16x8*>(qb + (long)(q0 + 16 + lc) * C_DIM + col_base + head * HD + lg * 8);

    const unsigned short* kbase = kb + (long)head * KT * 4096;
    const unsigned short* vbase = vt + (long)head * KT * 4096;

    f32x4 o00 = {0.f, 0.f, 0.f, 0.f}, o01 = {0.f, 0.f, 0.f, 0.f};
    f32x4 o10 = {0.f, 0.f, 0.f, 0.f}, o11 = {0.f, 0.f, 0.f, 0.f};
    float lsum0 = 0.f, lsum1 = 0.f;

    bf16x8 kf[8];
    bf16x8 vf0c[4], vf1c[4];
#pragma unroll
    for (int c = 0; c < 8; ++c)
        kf[c] = *reinterpret_cast<const bf16x8*>(kbase + (16 * c + lc) * 32 + lg * 8);
#pragma unroll
    for (int c2 = 0; c2 < 4; ++c2) {
        vf0c[c2] = *reinterpret_cast<const bf16x8*>(vbase + lc * 128 + c2 * 32 + lg * 8);
        vf1c[c2] = *reinterpret_cast<const bf16x8*>(vbase + (16 + lc) * 128 + c2 * 32 + lg * 8);
    }

    for (int kt = 0; kt < KT; ++kt) {
        f32x4 s0[8], s1[8];
        f32x4 z = {0.f, 0.f, 0.f, 0.f};
#pragma unroll
        for (int c = 0; c < 8; ++c) {
            s0[c] = __builtin_amdgcn_mfma_f32_16x16x32_bf16(kf[c], qf0, z, 0, 0, 0);
            s1[c] = __builtin_amdgcn_mfma_f32_16x16x32_bf16(kf[c], qf1, z, 0, 0, 0);
        }
        bf16x8 vf0n[4], vf1n[4];
        if (kt + 1 < KT) {
            const unsigned short* knext = kbase + (long)(kt + 1) * 4096;
            const unsigned short* vnext = vbase + (long)(kt + 1) * 4096;
#pragma unroll
            for (int c = 0; c < 8; ++c)
                kf[c] = *reinterpret_cast<const bf16x8*>(knext + (16 * c + lc) * 32 + lg * 8);
#pragma unroll
            for (int c2 = 0; c2 < 4; ++c2) {
                vf0n[c2] = *reinterpret_cast<const bf16x8*>(vnext + lc * 128 + c2 * 32 + lg * 8);
                vf1n[c2] = *reinterpret_cast<const bf16x8*>(vnext + (16 + lc) * 128 + c2 * 32 + lg * 8);
            }
        }
#pragma unroll
        for (int c2 = 0; c2 < 4; ++c2) {
            unsigned int w0, w1, w2, w3;
            {
                int c = 2 * c2;
                float p0 = __builtin_amdgcn_exp2f(s0[c][0]);
                float p1 = __builtin_amdgcn_exp2f(s0[c][1]);
                float p2 = __builtin_amdgcn_exp2f(s0[c][2]);
                float p3 = __builtin_amdgcn_exp2f(s0[c][3]);
                lsum0 += (p0 + p1) + (p2 + p3);
                w0 = cvtpk_bf16(p0, p1);
                w1 = cvtpk_bf16(p2, p3);
            }
            {
                int c = 2 * c2 + 1;
                float p0 = __builtin_amdgcn_exp2f(s0[c][0]);
                float p1 = __builtin_amdgcn_exp2f(s0[c][1]);
                float p2 = __builtin_amdgcn_exp2f(s0[c][2]);
                float p3 = __builtin_amdgcn_exp2f(s0[c][3]);
                lsum0 += (p0 + p1) + (p2 + p3);
                w2 = cvtpk_bf16(p0, p1);
                w3 = cvtpk_bf16(p2, p3);
            }
            u32x4 pw = {w0, w1, w2, w3};
            bf16x8 pa = __builtin_bit_cast(bf16x8, pw);
            o00 = __builtin_amdgcn_mfma_f32_16x16x32_bf16(pa, vf0c[c2], o00, 0, 0, 0);
            o01 = __builtin_amdgcn_mfma_f32_16x16x32_bf16(pa, vf1c[c2], o01, 0, 0, 0);
        }
#pragma unroll
        for (int c2 = 0; c2 < 4; ++c2) {
            unsigned int w0, w1, w2, w3;
            {
                int c = 2 * c2;
                float p0 = __builtin_amdgcn_exp2f(s1[c][0]);
                float p1 = __builtin_amdgcn_exp2f(s1[c][1]);
                float p2 = __builtin_amdgcn_exp2f(s1[c][2]);
                float p3 = __builtin_amdgcn_exp2f(s1[c][3]);
                lsum1 += (p0 + p1) + (p2 + p3);
                w0 = cvtpk_bf16(p0, p1);
                w1 = cvtpk_bf16(p2, p3);
            }
            {
                int c = 2 * c2 + 1;
                float p0 = __builtin_amdgcn_exp2f(s1[c][0]);
                float p1 = __builtin_amdgcn_exp2f(s1[c][1]);
                float p2 = __builtin_amdgcn_exp2f(s1[c][2]);
                float p3 = __builtin_amdgcn_exp2f(s1[c][3]);
                lsum1 += (p0 + p1) + (p2 + p3);
                w2 = cvtpk_bf16(p0, p1);
                w3 = cvtpk_bf16(p2, p3);
            }
            u32x4 pw = {w0, w1, w2, w3};
            bf16x8 pa = __builtin_bit_cast(bf16x8, pw);
            o10 = __builtin_amdgcn_mfma_f32_16x16x32_bf16(pa, vf0c[c2], o10, 0, 0, 0);
            o11 = __builtin_amdgcn_mfma_f32_16x16x32_bf16(pa, vf1c[c2], o11, 0, 0, 0);
        }
        if (kt + 1 < KT) {
#pragma unroll
            for (int c2 = 0; c2 < 4; ++c2) {
                vf0c[c2] = vf0n[c2];
                vf1c[c2] = vf1n[c2];
            }
        }
    }
    lsum0 += __shfl_xor(lsum0, 16);
    lsum0 += __shfl_xor(lsum0, 32);
    lsum1 += __shfl_xor(lsum1, 16);
    lsum1 += __shfl_xor(lsum1, 32);
#pragma unroll
    for (int r = 0; r < 4; ++r) {
        float ls = __shfl(lsum0, lg * 4 + r);
        float inv = 1.f / ls;
        int row = q0 + lg * 4 + r;
        catb[(long)row * C_DIM + col_base + head * HD + lc] = f2bf(o00[r] * inv);
        catb[(long)row * C_DIM + col_base + head * HD + 16 + lc] = f2bf(o01[r] * inv);
    }
#pragma unroll
    for (int r = 0; r < 4; ++r) {
        float ls = __shfl(lsum1, lg * 4 + r);
        float inv = 1.f / ls;
        int row = q0 + 16 + lg * 4 + r;
        catb[(long)row * C_DIM + col_base + head * HD + lc] = f2bf(o10[r] * inv);
        catb[(long)row * C_DIM + col_base + head * HD + 16 + lc] = f2bf(o11[r] * inv);
    }
}

// ---------------------------------------------------------------------------
extern "C" void kernel_launch(void* const* d_in, const int* in_sizes, int n_in,
                              void* d_out, int out_size, void* d_ws, size_t ws_size,
                              hipStream_t stream) {
    const float* x      = (const float*)d_in[0];
    const float* Wq     = (const float*)d_in[1];
    const float* sr1_w  = (const float*)d_in[2];
    const float* sr1_b  = (const float*)d_in[3];
    const float* ln1_w  = (const float*)d_in[4];
    const float* ln1_b  = (const float*)d_in[5];
    const float* sr2_w  = (const float*)d_in[6];
    const float* sr2_b  = (const float*)d_in[7];
    const float* ln2_w  = (const float*)d_in[8];
    const float* ln2_b  = (const float*)d_in[9];
    const float* Wkv1   = (const float*)d_in[10];
    const float* Wkv2   = (const float*)d_in[11];
    const float* lc1_w  = (const float*)d_in[12];
    const float* lc1_b  = (const float*)d_in[13];
    const float* lc2_w  = (const float*)d_in[14];
    const float* lc2_b  = (const float*)d_in[15];
    const float* proj_w = (const float*)d_in[16];
    const float* proj_b = (const float*)d_in[17];
    float* out = (float*)d_out;
    char* wsb = (char*)d_ws;

    // Workspace (~35.9 MB, proven available r4-r20):
    // buf0 (8 MB): part1 (8x0.5MB=4MB) + part2 (2x2MB=4MB @ +4MB) -> kv1part
    // im (8 MB): im2 -> kv2part
    // hi (8.4 MB): im1 (8 MB) -> catb (4 MB)
    float* buf0 = (float*)wsb;                                  // 8 MB
    unsigned short* qb = (unsigned short*)(wsb + 8388608);      // 4 MB
    float* im = (float*)(wsb + 12582912);                       // 8 MB
    float* xr1 = (float*)(wsb + 20971520);
    float* kv1 = (float*)(wsb + 21495808);
    unsigned short* kb1 = (unsigned short*)(wsb + 22020096);
    unsigned short* vt1 = (unsigned short*)(wsb + 22151168);
    float* xr2 = (float*)(wsb + 22282240);
    float* kv2 = (float*)(wsb + 24379392);
    unsigned short* kb2 = (unsigned short*)(wsb + 26476544);
    unsigned short* vt2 = (unsigned short*)(wsb + 27000832);
    float* hi = (float*)(wsb + 27525120);                       // 8.4 MB region

    float* im1 = hi;                       // 512 x 4096 f32 = 8 MB
    float* im2 = im;                       // 2048 x 1024 f32 = 8 MB
    float* part1 = buf0;                   // 8 x 512*256 f32 = 4 MB
    float* part2 = (float*)(wsb + 4194304);// 2 x 2048*256 f32 = 4 MB
    float* kv1part = buf0;                 // 8 x 0.5 MB (parts dead)
    float* kv2part = im;                   // 4 x 2 MB (im dead)
    unsigned short* catb = (unsigned short*)hi;  // 4 MB (im1 dead)

    // 1-2. im2col for both branches
    im2col_kernel<4><<<512, 256, 0, stream>>>(x, im1, 8);
    im2col_kernel<2><<<2048, 256, 0, stream>>>(x, im2, 16);

    // 3. fused Wq + sr1 + sr2 GEMMs (1024 blocks)
    qsr_fused_kernel<<<1024, 256, 0, stream>>>(x, Wq, qb, im1, sr1_w, part1, im2, sr2_w, part2);

    // 4. fused reduce + LN + GELU (both branches)
    reduce_ln_gelu_fused_kernel<<<2560, 256, 0, stream>>>(part1, sr1_b, ln1_w, ln1_b, xr1,
                                                          part2, sr2_b, ln2_w, ln2_b, xr2);

    // 5. fused kv GEMMs (768 blocks; partials into buf0/im, both dead)
    kv_fused_gemm_kernel<<<768, 256, 0, stream>>>(xr1, Wkv1, kv1part, xr2, Wkv2, kv2part);

    // 6. fused kv reduce (f32 kv + tiled bf16 K)
    reduce_kv_fused_kernel<<<2560, 256, 0, stream>>>(kv1part, kv1, kb1, kv2part, kv2, kb2);

    // 7. fused depthwise conv (both branches)
    dw_conv_fused_kernel<<<2560, 128, 0, stream>>>(kv1, lc1_w, lc1_b, vt1, kv2, lc2_w, lc2_b, vt2);

    // 8. fused attention -> bf16 cat (into hi; im1 dead)
    attn_fused_kernel<<<dim3(64, 8), 256, 0, stream>>>(qb, kb1, vt1, kb2, vt2, catb);

    // 9. out = cat @ proj_w.T + proj_b (bf16-A GEMM)
    gemm_projb_kernel<<<dim3(4, 128), 256, 0, stream>>>(catb, proj_w, proj_b, out, 8192, 256, 256);
}

// Round 24
// 96.705 us; speedup vs baseline: 1.2700x; 1.0316x over previous
//
#include <hip/hip_runtime.h>
#include <math.h>

#define C_DIM 256
#define HH 32
#define WW 32
#define ZZ 8
#define HD 32

typedef __attribute__((ext_vector_type(8))) short bf16x8;
typedef __attribute__((ext_vector_type(4))) float f32x4;
typedef __attribute__((ext_vector_type(4))) unsigned int u32x4;

__device__ inline unsigned short f2bf(float f) {
    unsigned int u = __builtin_bit_cast(unsigned int, f);
    u += 0x7FFF + ((u >> 16) & 1);
    return (unsigned short)(u >> 16);
}
__device__ inline unsigned int cvtpk_bf16(float a, float b) {
    unsigned int r;
    asm("v_cvt_pk_bf16_f32 %0, %1, %2" : "=v"(r) : "v"(a), "v"(b));
    return r;  // lo = bf16(a), hi = bf16(b)
}

// softmax scale with log2(e) folded in: exp2(q*k*QSCALE) == exp(q*k/sqrt(32))
#define QSCALE (0.17677669529663689f * 1.4426950408889634f)

// ---------------------------------------------------------------------------
// GEMM tile job (device fn) — verified r19-r23 inner loop.
// ---------------------------------------------------------------------------
__device__ __forceinline__ void gemm_job(
    const float* __restrict__ A, const float* __restrict__ B,
    const float* __restrict__ bias, float* __restrict__ C,
    int M, int N, int K, int KS, int z, int bx, int by,
    unsigned short* __restrict__ qb_out,
    unsigned short (*Ah)[2560], unsigned short (*Al)[2560],
    unsigned short (*Bh)[2560], unsigned short (*Bl)[2560]) {
    int t = threadIdx.x;
    int wave = t >> 6, lane = t & 63;
    int lg = lane >> 4, lc = lane & 15;
    int wm = wave >> 1, wn = wave & 1;
    int m0 = by * 64, n0 = bx * 64;
    int Kc = K / KS;
    int kbeg = z * Kc;
    float* Cz = C + (long)z * M * N;
    int srow = t >> 2, sc8 = (t & 3) * 8;
    const float* aBase = A + (long)(m0 + srow) * K + kbeg + sc8;
    const float* bBase = B + (long)(n0 + srow) * K + kbeg + sc8;
    int nIter = Kc / 32;

    f32x4 acc[2][2];
#pragma unroll
    for (int i = 0; i < 2; ++i)
#pragma unroll
        for (int j = 0; j < 2; ++j) acc[i][j] = (f32x4){0.f, 0.f, 0.f, 0.f};

    auto split8 = [](f32x4 v0, f32x4 v1, u32x4& hw, u32x4& lw) {
        float av[8] = {v0[0], v0[1], v0[2], v0[3], v1[0], v1[1], v1[2], v1[3]};
#pragma unroll
        for (int p = 0; p < 4; ++p) {
            float x0 = av[2 * p], x1 = av[2 * p + 1];
            unsigned int w = cvtpk_bf16(x0, x1);
            float h0 = __builtin_bit_cast(float, w << 16);
            float h1 = __builtin_bit_cast(float, w & 0xFFFF0000u);
            hw[p] = w;
            lw[p] = cvtpk_bf16(x0 - h0, x1 - h1);
        }
    };
    auto stage = [&](int buf, int k) {
        f32x4 a0 = *reinterpret_cast<const f32x4*>(aBase + k * 32);
        f32x4 a1 = *reinterpret_cast<const f32x4*>(aBase + k * 32 + 4);
        u32x4 hw, lw;
        split8(a0, a1, hw, lw);
        *reinterpret_cast<u32x4*>(&Ah[buf][srow * 40 + sc8]) = hw;
        *reinterpret_cast<u32x4*>(&Al[buf][srow * 40 + sc8]) = lw;
        f32x4 b0 = *reinterpret_cast<const f32x4*>(bBase + k * 32);
        f32x4 b1 = *reinterpret_cast<const f32x4*>(bBase + k * 32 + 4);
        split8(b0, b1, hw, lw);
        *reinterpret_cast<u32x4*>(&Bh[buf][srow * 40 + sc8]) = hw;
        *reinterpret_cast<u32x4*>(&Bl[buf][srow * 40 + sc8]) = lw;
    };

    stage(0, 0);
    __syncthreads();

    for (int k = 0; k < nIter; ++k) {
        int cur = k & 1;
        bool more = (k + 1 < nIter);
        bf16x8 afh[2], afl[2], bfh[2], bfl[2];
#pragma unroll
        for (int i = 0; i < 2; ++i) {
            int ar = wm * 32 + i * 16 + lc;
            afh[i] = *reinterpret_cast<const bf16x8*>(&Ah[cur][ar * 40 + lg * 8]);
            afl[i] = *reinterpret_cast<const bf16x8*>(&Al[cur][ar * 40 + lg * 8]);
            int br = wn * 32 + i * 16 + lc;
            bfh[i] = *reinterpret_cast<const bf16x8*>(&Bh[cur][br * 40 + lg * 8]);
            bfl[i] = *reinterpret_cast<const bf16x8*>(&Bl[cur][br * 40 + lg * 8]);
        }
#pragma unroll
        for (int i = 0; i < 2; ++i)
#pragma unroll
            for (int j = 0; j < 2; ++j) {
                acc[i][j] = __builtin_amdgcn_mfma_f32_16x16x32_bf16(afh[i], bfh[j], acc[i][j], 0, 0, 0);
                acc[i][j] = __builtin_amdgcn_mfma_f32_16x16x32_bf16(afh[i], bfl[j], acc[i][j], 0, 0, 0);
                acc[i][j] = __builtin_amdgcn_mfma_f32_16x16x32_bf16(afl[i], bfh[j], acc[i][j], 0, 0, 0);
            }
        if (more) {
            stage(cur ^ 1, k + 1);
            __syncthreads();
        }
    }
#pragma unroll
    for (int i = 0; i < 2; ++i)
#pragma unroll
        for (int j = 0; j < 2; ++j)
#pragma unroll
            for (int r = 0; r < 4; ++r) {
                int row = m0 + wm * 32 + i * 16 + lg * 4 + r;
                int col = n0 + wn * 32 + j * 16 + lc;
                float bv = bias ? bias[col] : 0.f;
                float val = acc[i][j][r] + bv;
                if (qb_out) {
                    qb_out[(long)row * N + col] = f2bf(val * QSCALE);
                } else {
                    Cz[(long)row * N + col] = val;
                }
            }
}

// ---------------------------------------------------------------------------
// Fused Wq + sr1 + sr2 GEMMs (1024 blocks).
// ---------------------------------------------------------------------------
__global__ __launch_bounds__(256) void qsr_fused_kernel(
    const float* __restrict__ x, const float* __restrict__ Wq,
    unsigned short* __restrict__ qb,
    const float* __restrict__ im1, const float* __restrict__ sr1_w, float* __restrict__ part1,
    const float* __restrict__ im2, const float* __restrict__ sr2_w, float* __restrict__ part2) {
    __shared__ unsigned short Ah[2][2560], Al[2][2560], Bh[2][2560], Bl[2][2560];
    int b = blockIdx.x;
    if (b < 512) {
        gemm_job(x, Wq, nullptr, nullptr, 8192, 256, 256, 1, 0, b & 3, b >> 2, qb, Ah, Al, Bh, Bl);
    } else if (b < 768) {
        int l = b - 512;
        gemm_job(im1, sr1_w, nullptr, part1, 512, 256, 4096, 8, l >> 5, l & 3, (l >> 2) & 7, nullptr, Ah, Al, Bh, Bl);
    } else {
        int l = b - 768;
        gemm_job(im2, sr2_w, nullptr, part2, 2048, 256, 1024, 2, l >> 7, l & 3, (l >> 2) & 31, nullptr, Ah, Al, Bh, Bl);
    }
}

// ---------------------------------------------------------------------------
// Fused kv1 + kv2 GEMMs (768 blocks).
// ---------------------------------------------------------------------------
__global__ __launch_bounds__(256) void kv_fused_gemm_kernel(
    const float* __restrict__ xr1, const float* __restrict__ Wkv1, float* __restrict__ kv1part,
    const float* __restrict__ xr2, const float* __restrict__ Wkv2, float* __restrict__ kv2part) {
    __shared__ unsigned short Ah[2][2560], Al[2][2560], Bh[2][2560], Bl[2][2560];
    int b = blockIdx.x;
    if (b < 256) {
        gemm_job(xr1, Wkv1, nullptr, kv1part, 512, 256, 256, 8, b >> 5, b & 3, (b >> 2) & 7, nullptr, Ah, Al, Bh, Bl);
    } else {
        int l = b - 256;
        gemm_job(xr2, Wkv2, nullptr, kv2part, 2048, 256, 256, 4, l >> 7, l & 3, (l >> 2) & 31, nullptr, Ah, Al, Bh, Bl);
    }
}

// ---------------------------------------------------------------------------
// proj GEMM: A is bf16 (exact), 2 MFMAs per (i,j).
// ---------------------------------------------------------------------------
__global__ __launch_bounds__(256) void gemm_projb_kernel(
    const unsigned short* __restrict__ A, const float* __restrict__ B,
    const float* __restrict__ bias, float* __restrict__ C, int M, int N, int K) {
    __shared__ unsigned short Ah[2][2560], Bh[2][2560], Bl[2][2560];
    int t = threadIdx.x;
    int wave = t >> 6, lane = t & 63;
    int lg = lane >> 4, lc = lane & 15;
    int wm = wave >> 1, wn = wave & 1;
    int m0 = blockIdx.y * 64, n0 = blockIdx.x * 64;
    int srow = t >> 2, sc8 = (t & 3) * 8;
    const unsigned short* aBase = A + (long)(m0 + srow) * K + sc8;
    const float* bBase = B + (long)(n0 + srow) * K + sc8;
    int nIter = K / 32;

    f32x4 acc[2][2];
#pragma unroll
    for (int i = 0; i < 2; ++i)
#pragma unroll
        for (int j = 0; j < 2; ++j) acc[i][j] = (f32x4){0.f, 0.f, 0.f, 0.f};

    auto split8 = [](f32x4 v0, f32x4 v1, u32x4& hw, u32x4& lw) {
        float av[8] = {v0[0], v0[1], v0[2], v0[3], v1[0], v1[1], v1[2], v1[3]};
#pragma unroll
        for (int p = 0; p < 4; ++p) {
            float x0 = av[2 * p], x1 = av[2 * p + 1];
            unsigned int w = cvtpk_bf16(x0, x1);
            float h0 = __builtin_bit_cast(float, w << 16);
            float h1 = __builtin_bit_cast(float, w & 0xFFFF0000u);
            hw[p] = w;
            lw[p] = cvtpk_bf16(x0 - h0, x1 - h1);
        }
    };
    auto stage = [&](int buf, int k) {
        u32x4 aw = *reinterpret_cast<const u32x4*>(aBase + k * 32);
        *reinterpret_cast<u32x4*>(&Ah[buf][srow * 40 + sc8]) = aw;
        f32x4 b0 = *reinterpret_cast<const f32x4*>(bBase + k * 32);
        f32x4 b1 = *reinterpret_cast<const f32x4*>(bBase + k * 32 + 4);
        u32x4 hw, lw;
        split8(b0, b1, hw, lw);
        *reinterpret_cast<u32x4*>(&Bh[buf][srow * 40 + sc8]) = hw;
        *reinterpret_cast<u32x4*>(&Bl[buf][srow * 40 + sc8]) = lw;
    };

    stage(0, 0);
    __syncthreads();

    for (int k = 0; k < nIter; ++k) {
        int cur = k & 1;
        bool more = (k + 1 < nIter);
        bf16x8 af[2], bfh[2], bfl[2];
#pragma unroll
        for (int i = 0; i < 2; ++i) {
            int ar = wm * 32 + i * 16 + lc;
            af[i] = *reinterpret_cast<const bf16x8*>(&Ah[cur][ar * 40 + lg * 8]);
            int br = wn * 32 + i * 16 + lc;
            bfh[i] = *reinterpret_cast<const bf16x8*>(&Bh[cur][br * 40 + lg * 8]);
            bfl[i] = *reinterpret_cast<const bf16x8*>(&Bl[cur][br * 40 + lg * 8]);
        }
#pragma unroll
        for (int i = 0; i < 2; ++i)
#pragma unroll
            for (int j = 0; j < 2; ++j) {
                acc[i][j] = __builtin_amdgcn_mfma_f32_16x16x32_bf16(af[i], bfh[j], acc[i][j], 0, 0, 0);
                acc[i][j] = __builtin_amdgcn_mfma_f32_16x16x32_bf16(af[i], bfl[j], acc[i][j], 0, 0, 0);
            }
        if (more) {
            stage(cur ^ 1, k + 1);
            __syncthreads();
        }
    }
#pragma unroll
    for (int i = 0; i < 2; ++i)
#pragma unroll
        for (int j = 0; j < 2; ++j)
#pragma unroll
            for (int r = 0; r < 4; ++r) {
                int row = m0 + wm * 32 + i * 16 + lg * 4 + r;
                int col = n0 + wn * 32 + j * 16 + lc;
                C[(long)row * N + col] = acc[i][j][r] + bias[col];
            }
}

// ---------------------------------------------------------------------------
// Fused (both branches): sum split-K planes + bias, LayerNorm + exact GELU.
// ---------------------------------------------------------------------------
__global__ void reduce_ln_gelu_fused_kernel(
    const float* __restrict__ p1, const float* __restrict__ b1f,
    const float* __restrict__ g1, const float* __restrict__ bb1, float* __restrict__ x1,
    const float* __restrict__ p2, const float* __restrict__ b2f,
    const float* __restrict__ g2, const float* __restrict__ bb2, float* __restrict__ x2) {
    int bx = blockIdx.x;
    int br1 = (bx < 512);
    int m = br1 ? bx : bx - 512;
    const float* part = br1 ? p1 : p2;
    const float* bias = br1 ? b1f : b2f;
    const float* g = br1 ? g1 : g2;
    const float* bb = br1 ? bb1 : bb2;
    float* xr = br1 ? x1 : x2;
    int MN = br1 ? 512 * 256 : 2048 * 256;
    int KS = br1 ? 8 : 2;

    int c = threadIdx.x;
    float v = bias[c];
    for (int z = 0; z < KS; ++z) v += part[(long)z * MN + m * C_DIM + c];
    __shared__ float wred[4];
    float s = v;
    for (int off = 32; off; off >>= 1) s += __shfl_down(s, off);
    if ((c & 63) == 0) wred[c >> 6] = s;
    __syncthreads();
    float mean = (wred[0] + wred[1] + wred[2] + wred[3]) * (1.f / 256.f);
    __syncthreads();
    float d = v - mean;
    float s2 = d * d;
    for (int off = 32; off; off >>= 1) s2 += __shfl_down(s2, off);
    if ((c & 63) == 0) wred[c >> 6] = s2;
    __syncthreads();
    float var = (wred[0] + wred[1] + wred[2] + wred[3]) * (1.f / 256.f);
    float y = d * rsqrtf(var + 1e-5f) * g[c] + bb[c];
    float ge = 0.5f * y * (1.f + erff(y * 0.70710678118654752f));
    xr[m * C_DIM + c] = ge;
}

// ---------------------------------------------------------------------------
// Fused kv reduce (both branches): f32 kv + tiled bf16 K.
// ---------------------------------------------------------------------------
__global__ void reduce_kv_fused_kernel(
    const float* __restrict__ p1, float* __restrict__ kv1, unsigned short* __restrict__ kb1,
    const float* __restrict__ p2, float* __restrict__ kv2, unsigned short* __restrict__ kb2) {
    int bx = blockIdx.x;
    int br1 = (bx < 512);
    int m = br1 ? bx : bx - 512;
    const float* part = br1 ? p1 : p2;
    float* kv = br1 ? kv1 : kv2;
    unsigned short* kb = br1 ? kb1 : kb2;
    int MN = br1 ? 512 * 256 : 2048 * 256;
    int KS = br1 ? 8 : 4;
    int KTp = br1 ? 4 : 16;

    int c = threadIdx.x;
    float v = 0.f;
    for (int z = 0; z < KS; ++z) v += part[(long)z * MN + m * C_DIM + c];
    kv[m * C_DIM + c] = v;
    if (c < 128) {
        int h = c >> 5, cc = c & 31, kt = m >> 7, mi = m & 127;
        kb[((long)(h * KTp + kt) * 128 + mi) * 32 + cc] = f2bf(v);
    }
}

// ---------------------------------------------------------------------------
// Fused im2col for BOTH branches. blocks 0..511: S=4 -> im1 (Ws=8);
// 512..2559: S=2 -> im2 (Ws=16). LDS sized for the larger (T=16) variant.
// ---------------------------------------------------------------------------
__device__ __forceinline__ void im2col_job(const float* __restrict__ x, float* __restrict__ im,
                                           int m, int Ws, int S, int T, float* patch) {
    int z = m % ZZ;
    int wo = (m / ZZ) % Ws;
    int ho = m / (ZZ * Ws);
    int t = threadIdx.x;
    for (int tap = 0; tap < T; ++tap) {
        int kh = tap / S, kw = tap % S;
        int row = (ho * S + kh) * (WW * ZZ) + (wo * S + kw) * ZZ + z;
        patch[tap * 257 + t] = x[row * C_DIM + t];
    }
    __syncthreads();
    for (int rep = 0; rep < T; ++rep) {
        int k = rep * 256 + t;
        int ci = k / T, tap = k % T;
        im[(long)m * (256 * T) + k] = patch[tap * 257 + ci];
    }
}

__global__ void im2col_fused_kernel(const float* __restrict__ x,
                                    float* __restrict__ im1, float* __restrict__ im2) {
    __shared__ float patch[16 * 257];
    int bx = blockIdx.x;
    if (bx < 512) {
        im2col_job(x, im1, bx, 8, 4, 16, patch);
    } else {
        im2col_job(x, im2, bx - 512, 16, 2, 4, patch);
    }
}

// ---------------------------------------------------------------------------
// Fused depthwise 3x3x1 conv on V + residual for BOTH branches (tiled V^T
// bf16 with the swapped-QK slot permutation).
// ---------------------------------------------------------------------------
__global__ void dw_conv_fused_kernel(const float* __restrict__ kv1, const float* __restrict__ lw1,
                                     const float* __restrict__ lb1, unsigned short* __restrict__ vt1,
                                     const float* __restrict__ kv2, const float* __restrict__ lw2,
                                     const float* __restrict__ lb2, unsigned short* __restrict__ vt2) {
    int bx = blockIdx.x;
    int b1 = (bx < 512);
    int m = b1 ? bx : bx - 512;
    const float* kv = b1 ? kv1 : kv2;
    const float* lw = b1 ? lw1 : lw2;
    const float* lb = b1 ? lb1 : lb2;
    unsigned short* vt = b1 ? vt1 : vt2;
    int Ws = b1 ? 8 : 16, Hs = b1 ? 8 : 16, KT = b1 ? 4 : 16;

    int ch = threadIdx.x;
    int z = m % ZZ;
    int wo = (m / ZZ) % Ws;
    int ho = m / (ZZ * Ws);
    float acc = lb[ch];
#pragma unroll
    for (int kh = 0; kh < 3; ++kh) {
        int h = ho + kh - 1;
        if (h < 0 || h >= Hs) continue;
#pragma unroll
        for (int kw = 0; kw < 3; ++kw) {
            int w2 = wo + kw - 1;
            if (w2 < 0 || w2 >= Ws) continue;
            int mm = (h * Ws + w2) * ZZ + z;
            acc += kv[mm * C_DIM + 128 + ch] * lw[ch * 9 + kh * 3 + kw];
        }
    }
    int hh = ch >> 5, d = ch & 31, kt = m >> 7, mi = m & 127;
    int a = mi >> 5, u = (mi >> 4) & 1, g = (mi >> 2) & 3, v = mi & 3;
    int s = (a << 5) | (g << 3) | (u << 2) | v;
    vt[((long)(hh * KT + kt) * 32 + d) * 128 + s] = f2bf(kv[m * C_DIM + 128 + ch] + acc);
}

// ---------------------------------------------------------------------------
// Fused MFMA flash attention (passing r18-r23 structure), bf16 output.
// ---------------------------------------------------------------------------
__global__ __launch_bounds__(256, 2) void attn_fused_kernel(
    const unsigned short* __restrict__ qb,
    const unsigned short* __restrict__ kb1, const unsigned short* __restrict__ vt1,
    const unsigned short* __restrict__ kb2, const unsigned short* __restrict__ vt2,
    unsigned short* __restrict__ catb) {
    int wave = threadIdx.x >> 6;
    int lane = threadIdx.x & 63;
    int lg = lane >> 4;
    int lc = lane & 15;
    int by = blockIdx.y;
    int big = ((by >> 2) == 0);
    int head = by & 3;
    const unsigned short* kb = big ? kb2 : kb1;
    const unsigned short* vt = big ? vt2 : vt1;
    int KT = big ? 16 : 4;
    int col_base = big ? 128 : 0;
    int q0 = blockIdx.x * 128 + wave * 32;

    bf16x8 qf0 = *reinterpret_cast<const bf16x8*>(qb + (long)(q0 + lc) * C_DIM + col_base + head * HD + lg * 8);
    bf16x8 qf1 = *reinterpret_cast<const bf16x8*>(qb + (long)(q0 + 16 + lc) * C_DIM + col_base + head * HD + lg * 8);

    const unsigned short* kbase = kb + (long)head * KT * 4096;
    const unsigned short* vbase = vt + (long)head * KT * 4096;

    f32x4 o00 = {0.f, 0.f, 0.f, 0.f}, o01 = {0.f, 0.f, 0.f, 0.f};
    f32x4 o10 = {0.f, 0.f, 0.f, 0.f}, o11 = {0.f, 0.f, 0.f, 0.f};
    float lsum0 = 0.f, lsum1 = 0.f;

    bf16x8 kf[8];
    bf16x8 vf0c[4], vf1c[4];
#pragma unroll
    for (int c = 0; c < 8; ++c)
        kf[c] = *reinterpret_cast<const bf16x8*>(kbase + (16 * c + lc) * 32 + lg * 8);
#pragma unroll
    for (int c2 = 0; c2 < 4; ++c2) {
        vf0c[c2] = *reinterpret_cast<const bf16x8*>(vbase + lc * 128 + c2 * 32 + lg * 8);
        vf1c[c2] = *reinterpret_cast<const bf16x8*>(vbase + (16 + lc) * 128 + c2 * 32 + lg * 8);
    }

    for (int kt = 0; kt < KT; ++kt) {
        f32x4 s0[8], s1[8];
        f32x4 z = {0.f, 0.f, 0.f, 0.f};
#pragma unroll
        for (int c = 0; c < 8; ++c) {
            s0[c] = __builtin_amdgcn_mfma_f32_16x16x32_bf16(kf[c], qf0, z, 0, 0, 0);
            s1[c] = __builtin_amdgcn_mfma_f32_16x16x32_bf16(kf[c], qf1, z, 0, 0, 0);
        }
        bf16x8 vf0n[4], vf1n[4];
        if (kt + 1 < KT) {
            const unsigned short* knext = kbase + (long)(kt + 1) * 4096;
            const unsigned short* vnext = vbase + (long)(kt + 1) * 4096;
#pragma unroll
            for (int c = 0; c < 8; ++c)
                kf[c] = *reinterpret_cast<const bf16x8*>(knext + (16 * c + lc) * 32 + lg * 8);
#pragma unroll
            for (int c2 = 0; c2 < 4; ++c2) {
                vf0n[c2] = *reinterpret_cast<const bf16x8*>(vnext + lc * 128 + c2 * 32 + lg * 8);
                vf1n[c2] = *reinterpret_cast<const bf16x8*>(vnext + (16 + lc) * 128 + c2 * 32 + lg * 8);
            }
        }
#pragma unroll
        for (int c2 = 0; c2 < 4; ++c2) {
            unsigned int w0, w1, w2, w3;
            {
                int c = 2 * c2;
                float p0 = __builtin_amdgcn_exp2f(s0[c][0]);
                float p1 = __builtin_amdgcn_exp2f(s0[c][1]);
                float p2 = __builtin_amdgcn_exp2f(s0[c][2]);
                float p3 = __builtin_amdgcn_exp2f(s0[c][3]);
                lsum0 += (p0 + p1) + (p2 + p3);
                w0 = cvtpk_bf16(p0, p1);
                w1 = cvtpk_bf16(p2, p3);
            }
            {
                int c = 2 * c2 + 1;
                float p0 = __builtin_amdgcn_exp2f(s0[c][0]);
                float p1 = __builtin_amdgcn_exp2f(s0[c][1]);
                float p2 = __builtin_amdgcn_exp2f(s0[c][2]);
                float p3 = __builtin_amdgcn_exp2f(s0[c][3]);
                lsum0 += (p0 + p1) + (p2 + p3);
                w2 = cvtpk_bf16(p0, p1);
                w3 = cvtpk_bf16(p2, p3);
            }
            u32x4 pw = {w0, w1, w2, w3};
            bf16x8 pa = __builtin_bit_cast(bf16x8, pw);
            o00 = __builtin_amdgcn_mfma_f32_16x16x32_bf16(pa, vf0c[c2], o00, 0, 0, 0);
            o01 = __builtin_amdgcn_mfma_f32_16x16x32_bf16(pa, vf1c[c2], o01, 0, 0, 0);
        }
#pragma unroll
        for (int c2 = 0; c2 < 4; ++c2) {
            unsigned int w0, w1, w2, w3;
            {
                int c = 2 * c2;
                float p0 = __builtin_amdgcn_exp2f(s1[c][0]);
                float p1 = __builtin_amdgcn_exp2f(s1[c][1]);
                float p2 = __builtin_amdgcn_exp2f(s1[c][2]);
                float p3 = __builtin_amdgcn_exp2f(s1[c][3]);
                lsum1 += (p0 + p1) + (p2 + p3);
                w0 = cvtpk_bf16(p0, p1);
                w1 = cvtpk_bf16(p2, p3);
            }
            {
                int c = 2 * c2 + 1;
                float p0 = __builtin_amdgcn_exp2f(s1[c][0]);
                float p1 = __builtin_amdgcn_exp2f(s1[c][1]);
                float p2 = __builtin_amdgcn_exp2f(s1[c][2]);
                float p3 = __builtin_amdgcn_exp2f(s1[c][3]);
                lsum1 += (p0 + p1) + (p2 + p3);
                w2 = cvtpk_bf16(p0, p1);
                w3 = cvtpk_bf16(p2, p3);
            }
            u32x4 pw = {w0, w1, w2, w3};
            bf16x8 pa = __builtin_bit_cast(bf16x8, pw);
            o10 = __builtin_amdgcn_mfma_f32_16x16x32_bf16(pa, vf0c[c2], o10, 0, 0, 0);
            o11 = __builtin_amdgcn_mfma_f32_16x16x32_bf16(pa, vf1c[c2], o11, 0, 0, 0);
        }
        if (kt + 1 < KT) {
#pragma unroll
            for (int c2 = 0; c2 < 4; ++c2) {
                vf0c[c2] = vf0n[c2];
                vf1c[c2] = vf1n[c2];
            }
        }
    }
    lsum0 += __shfl_xor(lsum0, 16);
    lsum0 += __shfl_xor(lsum0, 32);
    lsum1 += __shfl_xor(lsum1, 16);
    lsum1 += __shfl_xor(lsum1, 32);
#pragma unroll
    for (int r = 0; r < 4; ++r) {
        float ls = __shfl(lsum0, lg * 4 + r);
        float inv = 1.f / ls;
        int row = q0 + lg * 4 + r;
        catb[(long)row * C_DIM + col_base + head * HD + lc] = f2bf(o00[r] * inv);
        catb[(long)row * C_DIM + col_base + head * HD + 16 + lc] = f2bf(o01[r] * inv);
    }
#pragma unroll
    for (int r = 0; r < 4; ++r) {
        float ls = __shfl(lsum1, lg * 4 + r);
        float inv = 1.f / ls;
        int row = q0 + 16 + lg * 4 + r;
        catb[(long)row * C_DIM + col_base + head * HD + lc] = f2bf(o10[r] * inv);
        catb[(long)row * C_DIM + col_base + head * HD + 16 + lc] = f2bf(o11[r] * inv);
    }
}

// ---------------------------------------------------------------------------
extern "C" void kernel_launch(void* const* d_in, const int* in_sizes, int n_in,
                              void* d_out, int out_size, void* d_ws, size_t ws_size,
                              hipStream_t stream) {
    const float* x      = (const float*)d_in[0];
    const float* Wq     = (const float*)d_in[1];
    const float* sr1_w  = (const float*)d_in[2];
    const float* sr1_b  = (const float*)d_in[3];
    const float* ln1_w  = (const float*)d_in[4];
    const float* ln1_b  = (const float*)d_in[5];
    const float* sr2_w  = (const float*)d_in[6];
    const float* sr2_b  = (const float*)d_in[7];
    const float* ln2_w  = (const float*)d_in[8];
    const float* ln2_b  = (const float*)d_in[9];
    const float* Wkv1   = (const float*)d_in[10];
    const float* Wkv2   = (const float*)d_in[11];
    const float* lc1_w  = (const float*)d_in[12];
    const float* lc1_b  = (const float*)d_in[13];
    const float* lc2_w  = (const float*)d_in[14];
    const float* lc2_b  = (const float*)d_in[15];
    const float* proj_w = (const float*)d_in[16];
    const float* proj_b = (const float*)d_in[17];
    float* out = (float*)d_out;
    char* wsb = (char*)d_ws;

    // Workspace (~35.9 MB, proven available r4-r20):
    // buf0 (8 MB): part1 (4MB) + part2 (4MB @ +4MB) -> kv1part
    // im (8 MB): im2 -> kv2part
    // hi (8.4 MB): im1 (8 MB) -> catb (4 MB)
    float* buf0 = (float*)wsb;                                  // 8 MB
    unsigned short* qb = (unsigned short*)(wsb + 8388608);      // 4 MB
    float* im = (float*)(wsb + 12582912);                       // 8 MB
    float* xr1 = (float*)(wsb + 20971520);
    float* kv1 = (float*)(wsb + 21495808);
    unsigned short* kb1 = (unsigned short*)(wsb + 22020096);
    unsigned short* vt1 = (unsigned short*)(wsb + 22151168);
    float* xr2 = (float*)(wsb + 22282240);
    float* kv2 = (float*)(wsb + 24379392);
    unsigned short* kb2 = (unsigned short*)(wsb + 26476544);
    unsigned short* vt2 = (unsigned short*)(wsb + 27000832);
    float* hi = (float*)(wsb + 27525120);                       // 8.4 MB region

    float* im1 = hi;                        // 8 MB
    float* im2 = im;                        // 8 MB
    float* part1 = buf0;                    // 4 MB
    float* part2 = (float*)(wsb + 4194304); // 4 MB
    float* kv1part = buf0;                  // parts dead
    float* kv2part = im;                    // im dead
    unsigned short* catb = (unsigned short*)hi;  // im1 dead

    // 1. fused im2col (both branches, 2560 blocks)
    im2col_fused_kernel<<<2560, 256, 0, stream>>>(x, im1, im2);

    // 2. fused Wq + sr1 + sr2 GEMMs (1024 blocks)
    qsr_fused_kernel<<<1024, 256, 0, stream>>>(x, Wq, qb, im1, sr1_w, part1, im2, sr2_w, part2);

    // 3. fused reduce + LN + GELU (both branches)
    reduce_ln_gelu_fused_kernel<<<2560, 256, 0, stream>>>(part1, sr1_b, ln1_w, ln1_b, xr1,
                                                          part2, sr2_b, ln2_w, ln2_b, xr2);

    // 4. fused kv GEMMs (768 blocks)
    kv_fused_gemm_kernel<<<768, 256, 0, stream>>>(xr1, Wkv1, kv1part, xr2, Wkv2, kv2part);

    // 5. fused kv reduce (f32 kv + tiled bf16 K)
    reduce_kv_fused_kernel<<<2560, 256, 0, stream>>>(kv1part, kv1, kb1, kv2part, kv2, kb2);

    // 6. fused depthwise conv (both branches)
    dw_conv_fused_kernel<<<2560, 128, 0, stream>>>(kv1, lc1_w, lc1_b, vt1, kv2, lc2_w, lc2_b, vt2);

    // 7. fused attention -> bf16 cat (into hi; im1 dead)
    attn_fused_kernel<<<dim3(64, 8), 256, 0, stream>>>(qb, kb1, vt1, kb2, vt2, catb);

    // 8. out = cat @ proj_w.T + proj_b (bf16-A GEMM)
    gemm_projb_kernel<<<dim3(4, 128), 256, 0, stream>>>(catb, proj_w, proj_b, out, 8192, 256, 256);
}